// Round 3
// baseline (3428.167 us; speedup 1.0000x reference)
//
#include <hip/hip_runtime.h>
#include <hip/hip_bf16.h>
#include <math.h>

// ---------------------------------------------------------------------------
// Mamba2 mixer forward, MI355X. Round 3: dtype-adaptive inputs.
// R2 produced NaN; all-bf16 audit found no NaN path => inputs are likely fp32
// (fp32 read as bf16 gives ~1/256 Inf/NaN words -> NaN after K=2048 dots).
// detect_k classifies each input (bf16 vs fp32) at runtime; all input loads
// branch (wave-uniform) on per-tensor flags in ws. Output dtype = hs flag.
// Pipeline otherwise identical to R2 (vector GEMMs; MFMA next round).
// ---------------------------------------------------------------------------

#define B_SZ 2
#define L_SZ 2048
#define H_SZ 2048
#define I_SZ 4096
#define N_SZ 128
#define NH_SZ 64
#define P_SZ 64
#define CH_SZ 256
#define NC_SZ 8
#define PROJ_SZ 8512
#define CONV_SZ 4352
#define XOFF 4096   // xBC start inside proj row
#define DTOFF 8448  // dt start inside proj row
#define BOFF 4096   // B start inside convx row
#define COFF 4224   // C start inside convx row

__device__ __forceinline__ float bf2f(unsigned short u) {
  union { unsigned int i; float f; } v; v.i = ((unsigned int)u) << 16; return v.f;
}
__device__ __forceinline__ unsigned short f2bf(float f) {
  union { float f; unsigned int i; } v; v.f = f;
  unsigned int b = v.i + 0x7fffu + ((v.i >> 16) & 1u);
  return (unsigned short)(b >> 16);
}
__device__ __forceinline__ void unpack8(uint4 v, float* f) {
  f[0] = bf2f((unsigned short)(v.x & 0xffffu)); f[1] = bf2f((unsigned short)(v.x >> 16));
  f[2] = bf2f((unsigned short)(v.y & 0xffffu)); f[3] = bf2f((unsigned short)(v.y >> 16));
  f[4] = bf2f((unsigned short)(v.z & 0xffffu)); f[5] = bf2f((unsigned short)(v.z >> 16));
  f[6] = bf2f((unsigned short)(v.w & 0xffffu)); f[7] = bf2f((unsigned short)(v.w >> 16));
}
__device__ __forceinline__ float silu_f(float x) { return x / (1.f + expf(-x)); }

// Dual-dtype loads: fp32 flag chooses float vs bf16 element access.
__device__ __forceinline__ float load1(const void* p, long long e, int fp32) {
  return fp32 ? ((const float*)p)[e] : bf2f(((const unsigned short*)p)[e]);
}
__device__ __forceinline__ void load4(const void* p, long long e, int fp32, float* f) {
  if (fp32) {
    float4 a = *(const float4*)((const float*)p + e);
    f[0] = a.x; f[1] = a.y; f[2] = a.z; f[3] = a.w;
  } else {
    uint2 v = *(const uint2*)((const unsigned short*)p + e);
    f[0] = bf2f((unsigned short)(v.x & 0xffffu)); f[1] = bf2f((unsigned short)(v.x >> 16));
    f[2] = bf2f((unsigned short)(v.y & 0xffffu)); f[3] = bf2f((unsigned short)(v.y >> 16));
  }
}
__device__ __forceinline__ void load8(const void* p, long long e, int fp32, float* f) {
  if (fp32) {
    float4 a = *(const float4*)((const float*)p + e);
    float4 b = *(const float4*)((const float*)p + e + 4);
    f[0] = a.x; f[1] = a.y; f[2] = a.z; f[3] = a.w;
    f[4] = b.x; f[5] = b.y; f[6] = b.z; f[7] = b.w;
  } else {
    uint4 v = *(const uint4*)((const unsigned short*)p + e);
    unpack8(v, f);
  }
}

// ---------------------------------------------------------------------------
// Per-tensor dtype detector. For bf16 data, even-indexed ushorts are real
// elements (plausible exponent field); for fp32 data they are low mantissa
// halves (random exponent). fp32 <=> 2*plausible_even < plausible_odd.
// Robust to all-zero and ones-like tensors (fp32 ones: even halves all zero).
// ---------------------------------------------------------------------------
__global__ void detect_k(const void* p0, const void* p1, const void* p2,
                         const void* p3, const void* p4, const void* p5,
                         const void* p6, const void* p7, const void* p8,
                         int n0, int n1, int n2, int n3, int n4, int n5,
                         int n6, int n7, int n8, int* flags) {
  __shared__ int pe, po;
  const void* ps[9] = {p0, p1, p2, p3, p4, p5, p6, p7, p8};
  int ns[9] = {n0, n1, n2, n3, n4, n5, n6, n7, n8};
  int t = threadIdx.x;
  for (int i = 0; i < 9; i++) {
    if (t == 0) { pe = 0; po = 0; }
    __syncthreads();
    int S = ns[i] < 256 ? ns[i] : 256;
    if (t < S) {
      unsigned short u = ((const unsigned short*)ps[i])[t];
      int ex = (u >> 7) & 0xFF;
      int plaus = ((u & 0x7FFFu) != 0) && (ex >= 0x70) && (ex <= 0x8F);
      if (plaus) { if (t & 1) atomicAdd(&po, 1); else atomicAdd(&pe, 1); }
    }
    __syncthreads();
    if (t == 0) flags[i] = (2 * pe < po) ? 1 : 0;
    __syncthreads();
  }
  if (t == 0) { flags[14] = 0; flags[15] = 0; }  // internal buffers: bf16
}

// ---------------------------------------------------------------------------
// Generic C[M,N] = A[M,K] @ B[N,K]^T, fp32 acc, dtype per flags[fa]/flags[fb].
// OUT_MODE: 0 = bf16 out, 1 = fp32 out, 2 = runtime (flags[fo]: 1->fp32).
// 128x128 block tile, BK=16, 256 threads, 8x8 per thread, fp32 LDS tiles.
// ---------------------------------------------------------------------------
template <int OUT_MODE>
__global__ __launch_bounds__(256)
void gemm_bt_k(const void* __restrict__ A, const void* __restrict__ B,
               void* __restrict__ Cptr, int M, int N, int K,
               int lda, int ldb, int ldc,
               long long sA, long long sB, long long sC,
               const int* __restrict__ flags, int fa, int fb, int fo) {
  __shared__ float As[128][20];
  __shared__ float Bs[128][20];
  const int t = threadIdx.x;
  const int tx = t & 15, ty = t >> 4;
  const int m0 = blockIdx.y * 128, n0 = blockIdx.x * 128;
  const int afp = flags[fa], bfp = flags[fb];
  const int ofp = (OUT_MODE == 2) ? flags[fo] : (OUT_MODE == 1);
  const long long zoff = (long long)blockIdx.z;
  float* Cf = (float*)Cptr + zoff * sC;
  unsigned short* Cb = (unsigned short*)Cptr + zoff * sC;

  float acc[8][8];
#pragma unroll
  for (int i = 0; i < 8; i++)
#pragma unroll
    for (int j = 0; j < 8; j++) acc[i][j] = 0.f;

  const int rowS = t >> 1;        // 0..127
  const int kof  = (t & 1) * 8;   // 0 or 8
  const long long aRow = zoff * sA + (long long)(m0 + rowS) * lda + kof;
  const long long bRow = zoff * sB + (long long)(n0 + rowS) * ldb + kof;
  const bool bOK = (n0 + rowS) < N;

  for (int k0 = 0; k0 < K; k0 += 16) {
    float af[8], bf[8];
    load8(A, aRow + k0, afp, af);
    if (bOK) load8(B, bRow + k0, bfp, bf);
    else { bf[0]=bf[1]=bf[2]=bf[3]=bf[4]=bf[5]=bf[6]=bf[7]=0.f; }
    __syncthreads();
    *(float4*)&As[rowS][kof]     = make_float4(af[0], af[1], af[2], af[3]);
    *(float4*)&As[rowS][kof + 4] = make_float4(af[4], af[5], af[6], af[7]);
    *(float4*)&Bs[rowS][kof]     = make_float4(bf[0], bf[1], bf[2], bf[3]);
    *(float4*)&Bs[rowS][kof + 4] = make_float4(bf[4], bf[5], bf[6], bf[7]);
    __syncthreads();
#pragma unroll
    for (int kk = 0; kk < 16; kk += 2) {
      float2 a2[8], b2[8];
#pragma unroll
      for (int i = 0; i < 8; i++) a2[i] = *(const float2*)&As[ty + 16 * i][kk];
#pragma unroll
      for (int j = 0; j < 8; j++) b2[j] = *(const float2*)&Bs[tx + 16 * j][kk];
#pragma unroll
      for (int i = 0; i < 8; i++)
#pragma unroll
        for (int j = 0; j < 8; j++) {
          acc[i][j] = fmaf(a2[i].x, b2[j].x, acc[i][j]);
          acc[i][j] = fmaf(a2[i].y, b2[j].y, acc[i][j]);
        }
    }
  }
#pragma unroll
  for (int i = 0; i < 8; i++) {
    const int m = m0 + ty + 16 * i;
    const long long base = (long long)m * ldc;
#pragma unroll
    for (int j = 0; j < 8; j++) {
      const int n = n0 + tx + 16 * j;
      if (n < N) {
        if (ofp) Cf[base + n] = acc[i][j];
        else     Cb[base + n] = f2bf(acc[i][j]);
      }
    }
  }
}

// ---------------------------------------------------------------------------
// Depthwise causal conv (K=4) + bias + SiLU over xBC columns of proj.
// ---------------------------------------------------------------------------
__global__ __launch_bounds__(256)
void conv_silu_k(const unsigned short* __restrict__ proj,
                 const void* __restrict__ cw,
                 const void* __restrict__ cb,
                 unsigned short* __restrict__ convx,
                 const int* __restrict__ flags) {
  const int total = B_SZ * L_SZ * (CONV_SZ / 4);
  int g = blockIdx.x * 256 + threadIdx.x;
  if (g >= total) return;
  const int fw = flags[2], fb = flags[3];
  int c4 = g % (CONV_SZ / 4);
  int bl = g / (CONV_SZ / 4);
  int l = bl & (L_SZ - 1);
  int ch = c4 * 4;
  float w0[8], w1[8];
  load8(cw, (long long)ch * 4, fw, w0);      // ch taps0-3, ch+1 taps0-3
  load8(cw, (long long)ch * 4 + 8, fw, w1);  // ch+2, ch+3
  float accv[4];
  load4(cb, ch, fb, accv);
  float acc0 = accv[0], acc1 = accv[1], acc2 = accv[2], acc3 = accv[3];
  const long long rb = (long long)(bl - l);  // b*L
#pragma unroll
  for (int k = 0; k < 4; k++) {
    int ls = l - 3 + k;
    if (ls < 0) continue;
    uint2 xv = *(const uint2*)(proj + (rb + ls) * PROJ_SZ + XOFF + ch);
    float x0 = bf2f((unsigned short)(xv.x & 0xffffu));
    float x1 = bf2f((unsigned short)(xv.x >> 16));
    float x2 = bf2f((unsigned short)(xv.y & 0xffffu));
    float x3 = bf2f((unsigned short)(xv.y >> 16));
    acc0 = fmaf(x0, w0[k], acc0);
    acc1 = fmaf(x1, w0[4 + k], acc1);
    acc2 = fmaf(x2, w1[k], acc2);
    acc3 = fmaf(x3, w1[4 + k], acc3);
  }
  unsigned short o0 = f2bf(silu_f(acc0));
  unsigned short o1 = f2bf(silu_f(acc1));
  unsigned short o2 = f2bf(silu_f(acc2));
  unsigned short o3 = f2bf(silu_f(acc3));
  *(uint2*)(convx + (long long)bl * CONV_SZ + ch) =
      make_uint2((unsigned int)o0 | ((unsigned int)o1 << 16),
                 (unsigned int)o2 | ((unsigned int)o3 << 16));
}

// ---------------------------------------------------------------------------
// dt = softplus(dt_raw + dt_bias)
// ---------------------------------------------------------------------------
__global__ __launch_bounds__(256)
void dt_prep_k(const unsigned short* __restrict__ proj,
               const void* __restrict__ dt_bias,
               float* __restrict__ dtv, const int* __restrict__ flags) {
  int g = blockIdx.x * 256 + threadIdx.x;  // < 4096*64
  int h = g & 63;
  long long bl = g >> 6;
  float v = bf2f(proj[bl * PROJ_SZ + DTOFF + h]) + load1(dt_bias, h, flags[4]);
  float sp = (v > 20.f) ? v : log1pf(expf(v));
  dtv[g] = sp;
}

// ---------------------------------------------------------------------------
// Per-(b,chunk,head) inclusive cumsum of A*dt over the 256 chunk positions.
// ---------------------------------------------------------------------------
__global__ __launch_bounds__(256)
void acs_scan_k(const float* __restrict__ dtv,
                const void* __restrict__ A_log,
                float* __restrict__ acs, const int* __restrict__ flags) {
  __shared__ float sd[256];
  int blk = blockIdx.x;
  int h = blk & 63;
  int bc = blk >> 6;  // b*8+c
  int l = threadIdx.x;
  float Ah = -expf(load1(A_log, h, flags[5]));
  long long row = (long long)bc * CH_SZ + l;  // global (b,l) row
  sd[l] = Ah * dtv[row * NH_SZ + h];
  for (int off = 1; off < 256; off <<= 1) {
    __syncthreads();
    float tv = (l >= off) ? sd[l - off] : 0.f;
    __syncthreads();
    sd[l] += tv;
  }
  acs[(long long)blk * CH_SZ + l] = sd[l];
}

// ---------------------------------------------------------------------------
// Per-chunk states: stc[blk][p][n] = sum_l B[l,n] * exp(alast-acs[l]) * x[l,p]*dt[l]
// blk = ((b*8+c)*64+h). Thread owns 4 p x 8 n.
// ---------------------------------------------------------------------------
__global__ __launch_bounds__(256)
void chunk_states_k(const unsigned short* __restrict__ convx,
                    const float* __restrict__ dtv,
                    const float* __restrict__ acs,
                    float* __restrict__ stc) {
  __shared__ float Bw[32][128];
  __shared__ float xw[32][64];
  int blk = blockIdx.x;
  int h = blk & 63;
  int bc = blk >> 6;
  int t = threadIdx.x;
  const int p0 = (t & 15) * 4, n0 = (t >> 4) * 8;
  const float* acsb = acs + (long long)blk * 256;
  const float alast = acsb[255];
  float acc[4][8];
#pragma unroll
  for (int i = 0; i < 4; i++)
#pragma unroll
    for (int j = 0; j < 8; j++) acc[i][j] = 0.f;
  const long long row0 = (long long)bc * 256;

  for (int lt0 = 0; lt0 < 256; lt0 += 32) {
    __syncthreads();
#pragma unroll
    for (int q = 0; q < 4; q++) {
      int idx4 = (t + 256 * q) * 4;
      int r = idx4 >> 7, n = idx4 & 127;
      uint2 v = *(const uint2*)(convx + (row0 + lt0 + r) * CONV_SZ + BOFF + n);
      Bw[r][n]     = bf2f((unsigned short)(v.x & 0xffffu));
      Bw[r][n + 1] = bf2f((unsigned short)(v.x >> 16));
      Bw[r][n + 2] = bf2f((unsigned short)(v.y & 0xffffu));
      Bw[r][n + 3] = bf2f((unsigned short)(v.y >> 16));
    }
#pragma unroll
    for (int q = 0; q < 2; q++) {
      int idx4 = (t + 256 * q) * 4;
      int r = idx4 >> 6, p = idx4 & 63;
      long long lg = row0 + lt0 + r;
      float sc = dtv[lg * NH_SZ + h] * expf(alast - acsb[lt0 + r]);
      uint2 v = *(const uint2*)(convx + lg * CONV_SZ + h * 64 + p);
      xw[r][p]     = bf2f((unsigned short)(v.x & 0xffffu)) * sc;
      xw[r][p + 1] = bf2f((unsigned short)(v.x >> 16)) * sc;
      xw[r][p + 2] = bf2f((unsigned short)(v.y & 0xffffu)) * sc;
      xw[r][p + 3] = bf2f((unsigned short)(v.y >> 16)) * sc;
    }
    __syncthreads();
#pragma unroll 4
    for (int lt = 0; lt < 32; lt++) {
      float4 xv = *(const float4*)&xw[lt][p0];
      float4 b0 = *(const float4*)&Bw[lt][n0];
      float4 b1 = *(const float4*)&Bw[lt][n0 + 4];
      float xa[4] = {xv.x, xv.y, xv.z, xv.w};
      float ba[8] = {b0.x, b0.y, b0.z, b0.w, b1.x, b1.y, b1.z, b1.w};
#pragma unroll
      for (int i = 0; i < 4; i++)
#pragma unroll
        for (int j = 0; j < 8; j++) acc[i][j] = fmaf(xa[i], ba[j], acc[i][j]);
    }
  }
  float* outb = stc + (long long)blk * 8192;
#pragma unroll
  for (int i = 0; i < 4; i++) {
    *(float4*)&outb[(p0 + i) * 128 + n0] =
        make_float4(acc[i][0], acc[i][1], acc[i][2], acc[i][3]);
    *(float4*)&outb[(p0 + i) * 128 + n0 + 4] =
        make_float4(acc[i][4], acc[i][5], acc[i][6], acc[i][7]);
  }
}

// ---------------------------------------------------------------------------
// Inter-chunk recurrence, IN-PLACE on stc. block = b*64+h.
// After this kernel stc[bz] holds the state ENTERING chunk z (S_in).
// ---------------------------------------------------------------------------
__global__ __launch_bounds__(256)
void recur_k(float* __restrict__ stc, const float* __restrict__ acs) {
  int blk = blockIdx.x;
  int b = blk >> 6, h = blk & 63;
  int t = threadIdx.x;
  float S[32];
#pragma unroll
  for (int j = 0; j < 32; j++) S[j] = 0.f;
  for (int z = 0; z < 8; z++) {
    long long bz = ((long long)b * 8 + z) * 64 + h;
    long long base = bz * 8192;
    float e = expf(acs[bz * 256 + 255]);
#pragma unroll
    for (int j = 0; j < 32; j++) {
      int idx = j * 256 + t;
      float cs = stc[base + idx];
      stc[base + idx] = S[j];
      S[j] = fmaf(e, S[j], cs);
    }
  }
}

// ---------------------------------------------------------------------------
// y[l,p] = exp(acs[l]) * sum_n C[l,n]*SI[p,n]  +  D[h]*x[l,p]
// ---------------------------------------------------------------------------
__global__ __launch_bounds__(256)
void yoff_k(const unsigned short* __restrict__ convx,
            const float* __restrict__ sti,
            const float* __restrict__ acs,
            const void* __restrict__ Dw,
            float* __restrict__ y, const int* __restrict__ flags) {
  __shared__ float SIt[128][68];          // [n][p]
  __shared__ unsigned short Ct[64][128];  // [l][n]
  int blk = blockIdx.x;
  int h = blk & 63;
  int bc = blk >> 6;
  int t = threadIdx.x;
  const int txp = t & 15, lq = t >> 4;
  const float Dh = load1(Dw, h, flags[6]);
  const float* sib = sti + (long long)blk * 8192;
#pragma unroll 4
  for (int q = 0; q < 32; q++) {
    int idx = t + 256 * q;
    SIt[idx & 127][idx >> 7] = sib[idx];
  }
  const float* acsb = acs + (long long)blk * 256;
  const long long row0 = (long long)bc * 256;
  for (int ltile = 0; ltile < 4; ltile++) {
    __syncthreads();
#pragma unroll 4
    for (int q = 0; q < 32; q++) {
      int idx = t + 256 * q;
      int lr = idx >> 7, n = idx & 127;
      Ct[lr][n] = convx[(row0 + ltile * 64 + lr) * CONV_SZ + COFF + n];
    }
    __syncthreads();
    float acc[4][4] = {};
#pragma unroll 4
    for (int n = 0; n < 128; n++) {
      float4 sv = *(const float4*)&SIt[n][txp * 4];
      float c0 = bf2f(Ct[lq * 4 + 0][n]);
      float c1 = bf2f(Ct[lq * 4 + 1][n]);
      float c2 = bf2f(Ct[lq * 4 + 2][n]);
      float c3 = bf2f(Ct[lq * 4 + 3][n]);
      acc[0][0] = fmaf(c0, sv.x, acc[0][0]); acc[0][1] = fmaf(c0, sv.y, acc[0][1]);
      acc[0][2] = fmaf(c0, sv.z, acc[0][2]); acc[0][3] = fmaf(c0, sv.w, acc[0][3]);
      acc[1][0] = fmaf(c1, sv.x, acc[1][0]); acc[1][1] = fmaf(c1, sv.y, acc[1][1]);
      acc[1][2] = fmaf(c1, sv.z, acc[1][2]); acc[1][3] = fmaf(c1, sv.w, acc[1][3]);
      acc[2][0] = fmaf(c2, sv.x, acc[2][0]); acc[2][1] = fmaf(c2, sv.y, acc[2][1]);
      acc[2][2] = fmaf(c2, sv.z, acc[2][2]); acc[2][3] = fmaf(c2, sv.w, acc[2][3]);
      acc[3][0] = fmaf(c3, sv.x, acc[3][0]); acc[3][1] = fmaf(c3, sv.y, acc[3][1]);
      acc[3][2] = fmaf(c3, sv.z, acc[3][2]); acc[3][3] = fmaf(c3, sv.w, acc[3][3]);
    }
#pragma unroll
    for (int i = 0; i < 4; i++) {
      int lloc = ltile * 64 + lq * 4 + i;
      long long row = row0 + lloc;
      float ex = expf(acsb[lloc]);
      uint2 xv = *(const uint2*)(convx + row * CONV_SZ + h * 64 + txp * 4);
      float4 o;
      o.x = fmaf(ex, acc[i][0], Dh * bf2f((unsigned short)(xv.x & 0xffffu)));
      o.y = fmaf(ex, acc[i][1], Dh * bf2f((unsigned short)(xv.x >> 16)));
      o.z = fmaf(ex, acc[i][2], Dh * bf2f((unsigned short)(xv.y & 0xffffu)));
      o.w = fmaf(ex, acc[i][3], Dh * bf2f((unsigned short)(xv.y >> 16)));
      *(float4*)&y[row * I_SZ + h * 64 + txp * 4] = o;
    }
  }
}

// ---------------------------------------------------------------------------
// y[l,p] += sum_{s<=l} G[l,s]*exp(acs[l]-acs[s]) * x[s,p]*dt[s]
// ---------------------------------------------------------------------------
__global__ __launch_bounds__(256)
void ydiag_k(const unsigned short* __restrict__ convx,
             const float* __restrict__ dtv,
             const float* __restrict__ acs,
             const float* __restrict__ Gmat,
             float* __restrict__ y) {
  __shared__ float acs_s[256];
  __shared__ float xsT[64][68];  // [s][p]
  __shared__ float Mt[64][66];   // [l][s]
  int blk = blockIdx.x;
  int h = blk & 63;
  int bc = blk >> 6;
  int t = threadIdx.x;
  const int txp = t & 15, lq = t >> 4;
  acs_s[t] = acs[(long long)blk * 256 + t];
  const long long row0 = (long long)bc * 256;
  const float* Gb = Gmat + (long long)bc * 65536;
  for (int ltile = 0; ltile < 4; ltile++) {
    float acc[4][4] = {};
    for (int stile = 0; stile <= ltile; stile++) {
      __syncthreads();
#pragma unroll 4
      for (int q = 0; q < 16; q++) {
        int idx = t + 256 * q;
        int ss = idx >> 6, p = idx & 63;
        long long row = row0 + stile * 64 + ss;
        xsT[ss][p] = bf2f(convx[row * CONV_SZ + h * 64 + p]) * dtv[row * NH_SZ + h];
      }
#pragma unroll 4
      for (int q = 0; q < 16; q++) {
        int idx = t + 256 * q;
        int lr = idx >> 6, ss = idx & 63;
        int lg = ltile * 64 + lr, sg = stile * 64 + ss;
        float m = 0.f;
        if (sg <= lg) m = Gb[(long long)lg * 256 + sg] * expf(acs_s[lg] - acs_s[sg]);
        Mt[lr][ss] = m;
      }
      __syncthreads();
#pragma unroll 4
      for (int ss = 0; ss < 64; ss++) {
        float4 xv = *(const float4*)&xsT[ss][txp * 4];
        float m0 = Mt[lq * 4 + 0][ss];
        float m1 = Mt[lq * 4 + 1][ss];
        float m2 = Mt[lq * 4 + 2][ss];
        float m3 = Mt[lq * 4 + 3][ss];
        acc[0][0] = fmaf(m0, xv.x, acc[0][0]); acc[0][1] = fmaf(m0, xv.y, acc[0][1]);
        acc[0][2] = fmaf(m0, xv.z, acc[0][2]); acc[0][3] = fmaf(m0, xv.w, acc[0][3]);
        acc[1][0] = fmaf(m1, xv.x, acc[1][0]); acc[1][1] = fmaf(m1, xv.y, acc[1][1]);
        acc[1][2] = fmaf(m1, xv.z, acc[1][2]); acc[1][3] = fmaf(m1, xv.w, acc[1][3]);
        acc[2][0] = fmaf(m2, xv.x, acc[2][0]); acc[2][1] = fmaf(m2, xv.y, acc[2][1]);
        acc[2][2] = fmaf(m2, xv.z, acc[2][2]); acc[2][3] = fmaf(m2, xv.w, acc[2][3]);
        acc[3][0] = fmaf(m3, xv.x, acc[3][0]); acc[3][1] = fmaf(m3, xv.y, acc[3][1]);
        acc[3][2] = fmaf(m3, xv.z, acc[3][2]); acc[3][3] = fmaf(m3, xv.w, acc[3][3]);
      }
    }
#pragma unroll
    for (int i = 0; i < 4; i++) {
      long long row = row0 + ltile * 64 + lq * 4 + i;
      float* yp = &y[row * I_SZ + h * 64 + txp * 4];
      float4 cur = *(float4*)yp;
      cur.x += acc[i][0]; cur.y += acc[i][1]; cur.z += acc[i][2]; cur.w += acc[i][3];
      *(float4*)yp = cur;
    }
  }
}

// ---------------------------------------------------------------------------
// Gated RMSNorm: yf = (y*silu(z)) * rsqrt(mean((y*silu(z))^2)+1e-5) * norm_w
// ---------------------------------------------------------------------------
__global__ __launch_bounds__(256)
void norm_k(const float* __restrict__ y,
            const unsigned short* __restrict__ proj,
            const void* __restrict__ nw,
            unsigned short* __restrict__ yfb, const int* __restrict__ flags) {
  __shared__ float red[4];
  __shared__ float sc_s;
  int row = blockIdx.x;
  int t = threadIdx.x;
  const int fn = flags[7];
  const float* yr = y + (long long)row * I_SZ;
  const unsigned short* zr = proj + (long long)row * PROJ_SZ;
  float g[16];
  float ss = 0.f;
#pragma unroll
  for (int q = 0; q < 4; q++) {
    int i0 = q * 1024 + t * 4;
    float4 yv = *(const float4*)&yr[i0];
    uint2 zv = *(const uint2*)&zr[i0];
    float z0 = bf2f((unsigned short)(zv.x & 0xffffu));
    float z1 = bf2f((unsigned short)(zv.x >> 16));
    float z2 = bf2f((unsigned short)(zv.y & 0xffffu));
    float z3 = bf2f((unsigned short)(zv.y >> 16));
    float g0 = yv.x * silu_f(z0), g1 = yv.y * silu_f(z1);
    float g2 = yv.z * silu_f(z2), g3 = yv.w * silu_f(z3);
    g[q * 4 + 0] = g0; g[q * 4 + 1] = g1; g[q * 4 + 2] = g2; g[q * 4 + 3] = g3;
    ss += g0 * g0 + g1 * g1 + g2 * g2 + g3 * g3;
  }
#pragma unroll
  for (int off = 32; off > 0; off >>= 1) ss += __shfl_down(ss, off, 64);
  if ((t & 63) == 0) red[t >> 6] = ss;
  __syncthreads();
  if (t == 0) sc_s = rsqrtf((red[0] + red[1] + red[2] + red[3]) * (1.f / 4096.f) + 1e-5f);
  __syncthreads();
  float sc = sc_s;
#pragma unroll
  for (int q = 0; q < 4; q++) {
    int i0 = q * 1024 + t * 4;
    float nv[4];
    load4(nw, i0, fn, nv);
    unsigned short o0 = f2bf(g[q * 4 + 0] * sc * nv[0]);
    unsigned short o1 = f2bf(g[q * 4 + 1] * sc * nv[1]);
    unsigned short o2 = f2bf(g[q * 4 + 2] * sc * nv[2]);
    unsigned short o3 = f2bf(g[q * 4 + 3] * sc * nv[3]);
    *(uint2*)&yfb[(long long)row * I_SZ + i0] =
        make_uint2((unsigned int)o0 | ((unsigned int)o1 << 16),
                   (unsigned int)o2 | ((unsigned int)o3 << 16));
  }
}

// ---------------------------------------------------------------------------
extern "C" void kernel_launch(void* const* d_in, const int* in_sizes, int n_in,
                              void* d_out, int out_size, void* d_ws, size_t ws_size,
                              hipStream_t stream) {
  const void* hs     = d_in[0];
  const void* W_in   = d_in[1];
  const void* conv_w = d_in[2];
  const void* conv_b = d_in[3];
  const void* dt_b   = d_in[4];
  const void* A_log  = d_in[5];
  const void* Dw     = d_in[6];
  const void* nw     = d_in[7];
  const void* W_out  = d_in[8];

  char* ws = (char*)d_ws;
  size_t off = 0;
  auto alloc = [&](size_t bytes) -> void* {
    void* p = ws + off;
    off += (bytes + 255) & ~(size_t)255;
    return p;
  };
  const long long ML = (long long)B_SZ * L_SZ;  // 4096 rows
  int* flags = (int*)alloc(64);
  unsigned short* proj  = (unsigned short*)alloc(ML * PROJ_SZ * 2);             // 66.5 MB
  unsigned short* convx = (unsigned short*)alloc(ML * CONV_SZ * 2);             // 34 MB
  float* dtv  = (float*)alloc(ML * NH_SZ * 4);                                  // 1 MB
  float* acsb = (float*)alloc((long long)B_SZ * NC_SZ * NH_SZ * CH_SZ * 4);     // 1 MB
  float* Gm   = (float*)alloc((long long)B_SZ * NC_SZ * CH_SZ * CH_SZ * 4);     // 4 MB
  float* stc  = (float*)alloc((long long)B_SZ * NC_SZ * NH_SZ * P_SZ * N_SZ * 4);  // 32 MB
  float* yb   = (float*)alloc(ML * I_SZ * 4);                                   // 64 MB
  unsigned short* yfb = (unsigned short*)stc;  // alias: stc dead after yoff_k
  (void)n_in; (void)out_size;
  if (off > ws_size) return;  // distinct failure mode (absmax fail, not fault)

  dim3 blk(256);
  // 0. per-tensor dtype detection
  detect_k<<<1, blk, 0, stream>>>(hs, W_in, conv_w, conv_b, dt_b, A_log, Dw, nw, W_out,
                                  in_sizes[0], in_sizes[1], in_sizes[2], in_sizes[3],
                                  in_sizes[4], in_sizes[5], in_sizes[6], in_sizes[7],
                                  in_sizes[8], flags);
  // 1. in-proj: proj[4096,8512] = hs @ W_in^T   (bf16 out)
  gemm_bt_k<0><<<dim3(67, 32, 1), blk, 0, stream>>>(
      hs, W_in, proj, 4096, PROJ_SZ, H_SZ, H_SZ, H_SZ, PROJ_SZ, 0, 0, 0,
      flags, 0, 1, 15);
  // 2. conv + silu
  conv_silu_k<<<dim3((B_SZ * L_SZ * (CONV_SZ / 4) + 255) / 256), blk, 0, stream>>>(
      proj, conv_w, conv_b, convx, flags);
  // 3. dt
  dt_prep_k<<<dim3((unsigned)(ML * NH_SZ / 256)), blk, 0, stream>>>(proj, dt_b, dtv, flags);
  // 4. cumsum A*dt
  acs_scan_k<<<dim3(B_SZ * NC_SZ * NH_SZ), blk, 0, stream>>>(dtv, A_log, acsb, flags);
  // 5. G = Cc @ Bc^T per (b,chunk)  (fp32 out)
  gemm_bt_k<1><<<dim3(2, 2, 16), blk, 0, stream>>>(
      (const unsigned short*)convx + COFF, (const unsigned short*)convx + BOFF,
      Gm, 256, 256, 128, CONV_SZ, CONV_SZ, 256,
      (long long)256 * CONV_SZ, (long long)256 * CONV_SZ, 65536,
      flags, 15, 15, 15);
  // 6. per-chunk states
  chunk_states_k<<<dim3(1024), blk, 0, stream>>>(convx, dtv, acsb, stc);
  // 7. inter-chunk recurrence (in-place on stc)
  recur_k<<<dim3(B_SZ * NH_SZ), blk, 0, stream>>>(stc, acsb);
  // 8. Y_off + D*x
  yoff_k<<<dim3(1024), blk, 0, stream>>>(convx, stc, acsb, Dw, yb, flags);
  // 9. Y_diag
  ydiag_k<<<dim3(1024), blk, 0, stream>>>(convx, dtv, acsb, Gm, yb);
  // 10. gated RMSNorm (writes into stc's space)
  norm_k<<<dim3((unsigned)ML), blk, 0, stream>>>(yb, proj, nw, yfb, flags);
  // 11. out-proj: out = yf @ W_out^T; output dtype follows hidden_states flag
  gemm_bt_k<2><<<dim3(16, 32, 1), blk, 0, stream>>>(
      yfb, W_out, d_out, 4096, H_SZ, I_SZ, I_SZ, I_SZ, H_SZ, 0, 0, 0,
      flags, 15, 8, 0);
}

// Round 4
// 1030.758 us; speedup vs baseline: 3.3259x; 3.3259x over previous
//
#include <hip/hip_runtime.h>
#include <hip/hip_bf16.h>
#include <math.h>

// ---------------------------------------------------------------------------
// Mamba2 mixer forward, MI355X. Round 4: MFMA for the two big GEMMs.
// R3 passed (3428us); in-proj vector GEMM = 2390us @ 60 TF, MfmaUtil=0.
// gemm_mfma_k: 128x128 tile, BK=32, mfma_f32_16x16x32_bf16, 4 waves x 4x4
// tiles, dtype-adaptive fp32->bf16 conversion during LDS staging, LDS row
// stride 40 bf16 (bank-uniform for ds_read_b128 frags).
// Inputs confirmed fp32 (R2 NaN vs R3 pass); output fp32 (flag-driven).
// ---------------------------------------------------------------------------

#define B_SZ 2
#define L_SZ 2048
#define H_SZ 2048
#define I_SZ 4096
#define N_SZ 128
#define NH_SZ 64
#define P_SZ 64
#define CH_SZ 256
#define NC_SZ 8
#define PROJ_SZ 8512
#define CONV_SZ 4352
#define XOFF 4096   // xBC start inside proj row
#define DTOFF 8448  // dt start inside proj row
#define BOFF 4096   // B start inside convx row
#define COFF 4224   // C start inside convx row

typedef __attribute__((ext_vector_type(8))) short short8_t;   // 8 bf16 frag
typedef __attribute__((ext_vector_type(4))) float float4_t;   // MFMA acc

__device__ __forceinline__ float bf2f(unsigned short u) {
  union { unsigned int i; float f; } v; v.i = ((unsigned int)u) << 16; return v.f;
}
__device__ __forceinline__ unsigned short f2bf(float f) {
  union { float f; unsigned int i; } v; v.f = f;
  unsigned int b = v.i + 0x7fffu + ((v.i >> 16) & 1u);
  return (unsigned short)(b >> 16);
}
__device__ __forceinline__ void unpack8(uint4 v, float* f) {
  f[0] = bf2f((unsigned short)(v.x & 0xffffu)); f[1] = bf2f((unsigned short)(v.x >> 16));
  f[2] = bf2f((unsigned short)(v.y & 0xffffu)); f[3] = bf2f((unsigned short)(v.y >> 16));
  f[4] = bf2f((unsigned short)(v.z & 0xffffu)); f[5] = bf2f((unsigned short)(v.z >> 16));
  f[6] = bf2f((unsigned short)(v.w & 0xffffu)); f[7] = bf2f((unsigned short)(v.w >> 16));
}
__device__ __forceinline__ float silu_f(float x) { return x / (1.f + expf(-x)); }

// Dual-dtype loads: fp32 flag chooses float vs bf16 element access.
__device__ __forceinline__ float load1(const void* p, long long e, int fp32) {
  return fp32 ? ((const float*)p)[e] : bf2f(((const unsigned short*)p)[e]);
}
__device__ __forceinline__ void load4(const void* p, long long e, int fp32, float* f) {
  if (fp32) {
    float4 a = *(const float4*)((const float*)p + e);
    f[0] = a.x; f[1] = a.y; f[2] = a.z; f[3] = a.w;
  } else {
    uint2 v = *(const uint2*)((const unsigned short*)p + e);
    f[0] = bf2f((unsigned short)(v.x & 0xffffu)); f[1] = bf2f((unsigned short)(v.x >> 16));
    f[2] = bf2f((unsigned short)(v.y & 0xffffu)); f[3] = bf2f((unsigned short)(v.y >> 16));
  }
}
__device__ __forceinline__ void load8(const void* p, long long e, int fp32, float* f) {
  if (fp32) {
    float4 a = *(const float4*)((const float*)p + e);
    float4 b = *(const float4*)((const float*)p + e + 4);
    f[0] = a.x; f[1] = a.y; f[2] = a.z; f[3] = a.w;
    f[4] = b.x; f[5] = b.y; f[6] = b.z; f[7] = b.w;
  } else {
    uint4 v = *(const uint4*)((const unsigned short*)p + e);
    unpack8(v, f);
  }
}
// Load 16 consecutive elems as bf16 bit patterns (converting if fp32).
__device__ __forceinline__ void load16_bf(const void* p, long long e, int fp32,
                                          unsigned short* o) {
  if (fp32) {
    const float* ap = (const float*)p + e;
    float4 x0 = *(const float4*)(ap);
    float4 x1 = *(const float4*)(ap + 4);
    float4 x2 = *(const float4*)(ap + 8);
    float4 x3 = *(const float4*)(ap + 12);
    o[0] = f2bf(x0.x); o[1] = f2bf(x0.y); o[2] = f2bf(x0.z); o[3] = f2bf(x0.w);
    o[4] = f2bf(x1.x); o[5] = f2bf(x1.y); o[6] = f2bf(x1.z); o[7] = f2bf(x1.w);
    o[8] = f2bf(x2.x); o[9] = f2bf(x2.y); o[10] = f2bf(x2.z); o[11] = f2bf(x2.w);
    o[12] = f2bf(x3.x); o[13] = f2bf(x3.y); o[14] = f2bf(x3.z); o[15] = f2bf(x3.w);
  } else {
    const unsigned short* ap = (const unsigned short*)p + e;
    uint4 u0 = *(const uint4*)(ap);
    uint4 u1 = *(const uint4*)(ap + 8);
    unsigned int w[8] = {u0.x, u0.y, u0.z, u0.w, u1.x, u1.y, u1.z, u1.w};
#pragma unroll
    for (int i = 0; i < 8; i++) {
      o[2 * i] = (unsigned short)(w[i] & 0xffffu);
      o[2 * i + 1] = (unsigned short)(w[i] >> 16);
    }
  }
}

// ---------------------------------------------------------------------------
// Per-tensor dtype detector (unchanged from R3; confirmed working).
// ---------------------------------------------------------------------------
__global__ void detect_k(const void* p0, const void* p1, const void* p2,
                         const void* p3, const void* p4, const void* p5,
                         const void* p6, const void* p7, const void* p8,
                         int n0, int n1, int n2, int n3, int n4, int n5,
                         int n6, int n7, int n8, int* flags) {
  __shared__ int pe, po;
  const void* ps[9] = {p0, p1, p2, p3, p4, p5, p6, p7, p8};
  int ns[9] = {n0, n1, n2, n3, n4, n5, n6, n7, n8};
  int t = threadIdx.x;
  for (int i = 0; i < 9; i++) {
    if (t == 0) { pe = 0; po = 0; }
    __syncthreads();
    int S = ns[i] < 256 ? ns[i] : 256;
    if (t < S) {
      unsigned short u = ((const unsigned short*)ps[i])[t];
      int ex = (u >> 7) & 0xFF;
      int plaus = ((u & 0x7FFFu) != 0) && (ex >= 0x70) && (ex <= 0x8F);
      if (plaus) { if (t & 1) atomicAdd(&po, 1); else atomicAdd(&pe, 1); }
    }
    __syncthreads();
    if (t == 0) flags[i] = (2 * pe < po) ? 1 : 0;
    __syncthreads();
  }
  if (t == 0) { flags[14] = 0; flags[15] = 0; }  // internal buffers: bf16
}

// ---------------------------------------------------------------------------
// MFMA GEMM: C[M,N] = A[M,K] @ B[N,K]^T, bf16 MFMA, fp32 acc.
// 128x128 tile, BK=32, 256 thr (4 waves), each wave 64x64 (4x4 MFMA tiles).
// Staging converts fp32->bf16 in-register per flags. LDS stride 40 bf16.
// OUT_MODE: 0 = bf16 out, 2 = runtime (flags[fo]: 1->fp32).
// Requires M%128==0, K%32==0; N-edge guarded.
// ---------------------------------------------------------------------------
template <int OUT_MODE>
__global__ __launch_bounds__(256)
void gemm_mfma_k(const void* __restrict__ A, const void* __restrict__ B,
                 void* __restrict__ Cptr, int M, int N, int K,
                 int lda, int ldb, int ldc,
                 const int* __restrict__ flags, int fa, int fb, int fo) {
  __shared__ unsigned short As[128 * 40];
  __shared__ unsigned short Bs[128 * 40];
  const int t = threadIdx.x;
  const int lane = t & 63;
  const int wave = t >> 6;
  const int quad = lane >> 4;   // 0..3
  const int l16 = lane & 15;
  const int m0 = blockIdx.y * 128, n0 = blockIdx.x * 128;
  const int wm = (wave >> 1) * 64, wn = (wave & 1) * 64;
  const int afp = flags[fa], bfp = flags[fb];
  const int ofp = (OUT_MODE == 2) ? flags[fo] : 0;

  float4_t acc[4][4];
#pragma unroll
  for (int i = 0; i < 4; i++)
#pragma unroll
    for (int j = 0; j < 4; j++) acc[i][j] = (float4_t){0.f, 0.f, 0.f, 0.f};

  // staging assignment: thread t -> row sr = t>>1 (0..127), 16-elem seg sk
  const int sr = t >> 1;
  const int sk = (t & 1) * 16;
  const long long aOff = (long long)(m0 + sr) * lda + sk;
  const long long bOff = (long long)(n0 + sr) * ldb + sk;
  const bool bOK = (n0 + sr) < N;
  unsigned short* asd = &As[sr * 40 + sk];
  unsigned short* bsd = &Bs[sr * 40 + sk];

  for (int k0 = 0; k0 < K; k0 += 32) {
    unsigned short av[16], bv[16];
    load16_bf(A, aOff + k0, afp, av);
    if (bOK) load16_bf(B, bOff + k0, bfp, bv);
    else {
#pragma unroll
      for (int i = 0; i < 16; i++) bv[i] = 0;
    }
    __syncthreads();  // previous iteration's frag reads done
    *(short8_t*)(asd)     = *(const short8_t*)(av);
    *(short8_t*)(asd + 8) = *(const short8_t*)(av + 8);
    *(short8_t*)(bsd)     = *(const short8_t*)(bv);
    *(short8_t*)(bsd + 8) = *(const short8_t*)(bv + 8);
    __syncthreads();
    short8_t afr[4], bfr[4];
#pragma unroll
    for (int i = 0; i < 4; i++)
      afr[i] = *(const short8_t*)&As[(wm + i * 16 + l16) * 40 + quad * 8];
#pragma unroll
    for (int j = 0; j < 4; j++)
      bfr[j] = *(const short8_t*)&Bs[(wn + j * 16 + l16) * 40 + quad * 8];
#pragma unroll
    for (int i = 0; i < 4; i++)
#pragma unroll
      for (int j = 0; j < 4; j++)
        acc[i][j] = __builtin_amdgcn_mfma_f32_16x16x32_bf16(
            afr[i], bfr[j], acc[i][j], 0, 0, 0);
  }
  // epilogue: D[m = quad*4+r][n = l16] per 16x16 tile
#pragma unroll
  for (int i = 0; i < 4; i++) {
#pragma unroll
    for (int r = 0; r < 4; r++) {
      const int m = m0 + wm + i * 16 + quad * 4 + r;
      const long long base = (long long)m * ldc;
#pragma unroll
      for (int j = 0; j < 4; j++) {
        const int n = n0 + wn + j * 16 + l16;
        if (n < N) {
          float v = acc[i][j][r];
          if (ofp) ((float*)Cptr)[base + n] = v;
          else     ((unsigned short*)Cptr)[base + n] = f2bf(v);
        }
      }
    }
  }
}

// ---------------------------------------------------------------------------
// Vector GEMM (kept for the small G = Cc@Bc^T batch). fp32 acc.
// OUT_MODE: 1 = fp32 out.
// ---------------------------------------------------------------------------
template <int OUT_MODE>
__global__ __launch_bounds__(256)
void gemm_bt_k(const void* __restrict__ A, const void* __restrict__ B,
               void* __restrict__ Cptr, int M, int N, int K,
               int lda, int ldb, int ldc,
               long long sA, long long sB, long long sC,
               const int* __restrict__ flags, int fa, int fb, int fo) {
  __shared__ float As[128][20];
  __shared__ float Bs[128][20];
  const int t = threadIdx.x;
  const int tx = t & 15, ty = t >> 4;
  const int m0 = blockIdx.y * 128, n0 = blockIdx.x * 128;
  const int afp = flags[fa], bfp = flags[fb];
  const int ofp = (OUT_MODE == 2) ? flags[fo] : (OUT_MODE == 1);
  const long long zoff = (long long)blockIdx.z;
  float* Cf = (float*)Cptr + zoff * sC;
  unsigned short* Cb = (unsigned short*)Cptr + zoff * sC;

  float acc[8][8];
#pragma unroll
  for (int i = 0; i < 8; i++)
#pragma unroll
    for (int j = 0; j < 8; j++) acc[i][j] = 0.f;

  const int rowS = t >> 1;
  const int kof  = (t & 1) * 8;
  const long long aRow = zoff * sA + (long long)(m0 + rowS) * lda + kof;
  const long long bRow = zoff * sB + (long long)(n0 + rowS) * ldb + kof;
  const bool bOK = (n0 + rowS) < N;

  for (int k0 = 0; k0 < K; k0 += 16) {
    float af[8], bf[8];
    load8(A, aRow + k0, afp, af);
    if (bOK) load8(B, bRow + k0, bfp, bf);
    else { bf[0]=bf[1]=bf[2]=bf[3]=bf[4]=bf[5]=bf[6]=bf[7]=0.f; }
    __syncthreads();
    *(float4*)&As[rowS][kof]     = make_float4(af[0], af[1], af[2], af[3]);
    *(float4*)&As[rowS][kof + 4] = make_float4(af[4], af[5], af[6], af[7]);
    *(float4*)&Bs[rowS][kof]     = make_float4(bf[0], bf[1], bf[2], bf[3]);
    *(float4*)&Bs[rowS][kof + 4] = make_float4(bf[4], bf[5], bf[6], bf[7]);
    __syncthreads();
#pragma unroll
    for (int kk = 0; kk < 16; kk += 2) {
      float2 a2[8], b2[8];
#pragma unroll
      for (int i = 0; i < 8; i++) a2[i] = *(const float2*)&As[ty + 16 * i][kk];
#pragma unroll
      for (int j = 0; j < 8; j++) b2[j] = *(const float2*)&Bs[tx + 16 * j][kk];
#pragma unroll
      for (int i = 0; i < 8; i++)
#pragma unroll
        for (int j = 0; j < 8; j++) {
          acc[i][j] = fmaf(a2[i].x, b2[j].x, acc[i][j]);
          acc[i][j] = fmaf(a2[i].y, b2[j].y, acc[i][j]);
        }
    }
  }
#pragma unroll
  for (int i = 0; i < 8; i++) {
    const int m = m0 + ty + 16 * i;
    const long long base = (long long)m * ldc;
#pragma unroll
    for (int j = 0; j < 8; j++) {
      const int n = n0 + tx + 16 * j;
      if (n < N) {
        if (ofp) Cf[base + n] = acc[i][j];
        else     Cb[base + n] = f2bf(acc[i][j]);
      }
    }
  }
}

// ---------------------------------------------------------------------------
// Depthwise causal conv (K=4) + bias + SiLU over xBC columns of proj.
// ---------------------------------------------------------------------------
__global__ __launch_bounds__(256)
void conv_silu_k(const unsigned short* __restrict__ proj,
                 const void* __restrict__ cw,
                 const void* __restrict__ cb,
                 unsigned short* __restrict__ convx,
                 const int* __restrict__ flags) {
  const int total = B_SZ * L_SZ * (CONV_SZ / 4);
  int g = blockIdx.x * 256 + threadIdx.x;
  if (g >= total) return;
  const int fw = flags[2], fb = flags[3];
  int c4 = g % (CONV_SZ / 4);
  int bl = g / (CONV_SZ / 4);
  int l = bl & (L_SZ - 1);
  int ch = c4 * 4;
  float w0[8], w1[8];
  load8(cw, (long long)ch * 4, fw, w0);
  load8(cw, (long long)ch * 4 + 8, fw, w1);
  float accv[4];
  load4(cb, ch, fb, accv);
  float acc0 = accv[0], acc1 = accv[1], acc2 = accv[2], acc3 = accv[3];
  const long long rb = (long long)(bl - l);
#pragma unroll
  for (int k = 0; k < 4; k++) {
    int ls = l - 3 + k;
    if (ls < 0) continue;
    uint2 xv = *(const uint2*)(proj + (rb + ls) * PROJ_SZ + XOFF + ch);
    float x0 = bf2f((unsigned short)(xv.x & 0xffffu));
    float x1 = bf2f((unsigned short)(xv.x >> 16));
    float x2 = bf2f((unsigned short)(xv.y & 0xffffu));
    float x3 = bf2f((unsigned short)(xv.y >> 16));
    acc0 = fmaf(x0, w0[k], acc0);
    acc1 = fmaf(x1, w0[4 + k], acc1);
    acc2 = fmaf(x2, w1[k], acc2);
    acc3 = fmaf(x3, w1[4 + k], acc3);
  }
  unsigned short o0 = f2bf(silu_f(acc0));
  unsigned short o1 = f2bf(silu_f(acc1));
  unsigned short o2 = f2bf(silu_f(acc2));
  unsigned short o3 = f2bf(silu_f(acc3));
  *(uint2*)(convx + (long long)bl * CONV_SZ + ch) =
      make_uint2((unsigned int)o0 | ((unsigned int)o1 << 16),
                 (unsigned int)o2 | ((unsigned int)o3 << 16));
}

// ---------------------------------------------------------------------------
__global__ __launch_bounds__(256)
void dt_prep_k(const unsigned short* __restrict__ proj,
               const void* __restrict__ dt_bias,
               float* __restrict__ dtv, const int* __restrict__ flags) {
  int g = blockIdx.x * 256 + threadIdx.x;
  int h = g & 63;
  long long bl = g >> 6;
  float v = bf2f(proj[bl * PROJ_SZ + DTOFF + h]) + load1(dt_bias, h, flags[4]);
  float sp = (v > 20.f) ? v : log1pf(expf(v));
  dtv[g] = sp;
}

// ---------------------------------------------------------------------------
__global__ __launch_bounds__(256)
void acs_scan_k(const float* __restrict__ dtv,
                const void* __restrict__ A_log,
                float* __restrict__ acs, const int* __restrict__ flags) {
  __shared__ float sd[256];
  int blk = blockIdx.x;
  int h = blk & 63;
  int bc = blk >> 6;
  int l = threadIdx.x;
  float Ah = -expf(load1(A_log, h, flags[5]));
  long long row = (long long)bc * CH_SZ + l;
  sd[l] = Ah * dtv[row * NH_SZ + h];
  for (int off = 1; off < 256; off <<= 1) {
    __syncthreads();
    float tv = (l >= off) ? sd[l - off] : 0.f;
    __syncthreads();
    sd[l] += tv;
  }
  acs[(long long)blk * CH_SZ + l] = sd[l];
}

// ---------------------------------------------------------------------------
__global__ __launch_bounds__(256)
void chunk_states_k(const unsigned short* __restrict__ convx,
                    const float* __restrict__ dtv,
                    const float* __restrict__ acs,
                    float* __restrict__ stc) {
  __shared__ float Bw[32][128];
  __shared__ float xw[32][64];
  int blk = blockIdx.x;
  int h = blk & 63;
  int bc = blk >> 6;
  int t = threadIdx.x;
  const int p0 = (t & 15) * 4, n0 = (t >> 4) * 8;
  const float* acsb = acs + (long long)blk * 256;
  const float alast = acsb[255];
  float acc[4][8];
#pragma unroll
  for (int i = 0; i < 4; i++)
#pragma unroll
    for (int j = 0; j < 8; j++) acc[i][j] = 0.f;
  const long long row0 = (long long)bc * 256;

  for (int lt0 = 0; lt0 < 256; lt0 += 32) {
    __syncthreads();
#pragma unroll
    for (int q = 0; q < 4; q++) {
      int idx4 = (t + 256 * q) * 4;
      int r = idx4 >> 7, n = idx4 & 127;
      uint2 v = *(const uint2*)(convx + (row0 + lt0 + r) * CONV_SZ + BOFF + n);
      Bw[r][n]     = bf2f((unsigned short)(v.x & 0xffffu));
      Bw[r][n + 1] = bf2f((unsigned short)(v.x >> 16));
      Bw[r][n + 2] = bf2f((unsigned short)(v.y & 0xffffu));
      Bw[r][n + 3] = bf2f((unsigned short)(v.y >> 16));
    }
#pragma unroll
    for (int q = 0; q < 2; q++) {
      int idx4 = (t + 256 * q) * 4;
      int r = idx4 >> 6, p = idx4 & 63;
      long long lg = row0 + lt0 + r;
      float sc = dtv[lg * NH_SZ + h] * expf(alast - acsb[lt0 + r]);
      uint2 v = *(const uint2*)(convx + lg * CONV_SZ + h * 64 + p);
      xw[r][p]     = bf2f((unsigned short)(v.x & 0xffffu)) * sc;
      xw[r][p + 1] = bf2f((unsigned short)(v.x >> 16)) * sc;
      xw[r][p + 2] = bf2f((unsigned short)(v.y & 0xffffu)) * sc;
      xw[r][p + 3] = bf2f((unsigned short)(v.y >> 16)) * sc;
    }
    __syncthreads();
#pragma unroll 4
    for (int lt = 0; lt < 32; lt++) {
      float4 xv = *(const float4*)&xw[lt][p0];
      float4 b0 = *(const float4*)&Bw[lt][n0];
      float4 b1 = *(const float4*)&Bw[lt][n0 + 4];
      float xa[4] = {xv.x, xv.y, xv.z, xv.w};
      float ba[8] = {b0.x, b0.y, b0.z, b0.w, b1.x, b1.y, b1.z, b1.w};
#pragma unroll
      for (int i = 0; i < 4; i++)
#pragma unroll
        for (int j = 0; j < 8; j++) acc[i][j] = fmaf(xa[i], ba[j], acc[i][j]);
    }
  }
  float* outb = stc + (long long)blk * 8192;
#pragma unroll
  for (int i = 0; i < 4; i++) {
    *(float4*)&outb[(p0 + i) * 128 + n0] =
        make_float4(acc[i][0], acc[i][1], acc[i][2], acc[i][3]);
    *(float4*)&outb[(p0 + i) * 128 + n0 + 4] =
        make_float4(acc[i][4], acc[i][5], acc[i][6], acc[i][7]);
  }
}

// ---------------------------------------------------------------------------
__global__ __launch_bounds__(256)
void recur_k(float* __restrict__ stc, const float* __restrict__ acs) {
  int blk = blockIdx.x;
  int b = blk >> 6, h = blk & 63;
  int t = threadIdx.x;
  float S[32];
#pragma unroll
  for (int j = 0; j < 32; j++) S[j] = 0.f;
  for (int z = 0; z < 8; z++) {
    long long bz = ((long long)b * 8 + z) * 64 + h;
    long long base = bz * 8192;
    float e = expf(acs[bz * 256 + 255]);
#pragma unroll
    for (int j = 0; j < 32; j++) {
      int idx = j * 256 + t;
      float cs = stc[base + idx];
      stc[base + idx] = S[j];
      S[j] = fmaf(e, S[j], cs);
    }
  }
}

// ---------------------------------------------------------------------------
__global__ __launch_bounds__(256)
void yoff_k(const unsigned short* __restrict__ convx,
            const float* __restrict__ sti,
            const float* __restrict__ acs,
            const void* __restrict__ Dw,
            float* __restrict__ y, const int* __restrict__ flags) {
  __shared__ float SIt[128][68];
  __shared__ unsigned short Ct[64][128];
  int blk = blockIdx.x;
  int h = blk & 63;
  int bc = blk >> 6;
  int t = threadIdx.x;
  const int txp = t & 15, lq = t >> 4;
  const float Dh = load1(Dw, h, flags[6]);
  const float* sib = sti + (long long)blk * 8192;
#pragma unroll 4
  for (int q = 0; q < 32; q++) {
    int idx = t + 256 * q;
    SIt[idx & 127][idx >> 7] = sib[idx];
  }
  const float* acsb = acs + (long long)blk * 256;
  const long long row0 = (long long)bc * 256;
  for (int ltile = 0; ltile < 4; ltile++) {
    __syncthreads();
#pragma unroll 4
    for (int q = 0; q < 32; q++) {
      int idx = t + 256 * q;
      int lr = idx >> 7, n = idx & 127;
      Ct[lr][n] = convx[(row0 + ltile * 64 + lr) * CONV_SZ + COFF + n];
    }
    __syncthreads();
    float acc[4][4] = {};
#pragma unroll 4
    for (int n = 0; n < 128; n++) {
      float4 sv = *(const float4*)&SIt[n][txp * 4];
      float c0 = bf2f(Ct[lq * 4 + 0][n]);
      float c1 = bf2f(Ct[lq * 4 + 1][n]);
      float c2 = bf2f(Ct[lq * 4 + 2][n]);
      float c3 = bf2f(Ct[lq * 4 + 3][n]);
      acc[0][0] = fmaf(c0, sv.x, acc[0][0]); acc[0][1] = fmaf(c0, sv.y, acc[0][1]);
      acc[0][2] = fmaf(c0, sv.z, acc[0][2]); acc[0][3] = fmaf(c0, sv.w, acc[0][3]);
      acc[1][0] = fmaf(c1, sv.x, acc[1][0]); acc[1][1] = fmaf(c1, sv.y, acc[1][1]);
      acc[1][2] = fmaf(c1, sv.z, acc[1][2]); acc[1][3] = fmaf(c1, sv.w, acc[1][3]);
      acc[2][0] = fmaf(c2, sv.x, acc[2][0]); acc[2][1] = fmaf(c2, sv.y, acc[2][1]);
      acc[2][2] = fmaf(c2, sv.z, acc[2][2]); acc[2][3] = fmaf(c2, sv.w, acc[2][3]);
      acc[3][0] = fmaf(c3, sv.x, acc[3][0]); acc[3][1] = fmaf(c3, sv.y, acc[3][1]);
      acc[3][2] = fmaf(c3, sv.z, acc[3][2]); acc[3][3] = fmaf(c3, sv.w, acc[3][3]);
    }
#pragma unroll
    for (int i = 0; i < 4; i++) {
      int lloc = ltile * 64 + lq * 4 + i;
      long long row = row0 + lloc;
      float ex = expf(acsb[lloc]);
      uint2 xv = *(const uint2*)(convx + row * CONV_SZ + h * 64 + txp * 4);
      float4 o;
      o.x = fmaf(ex, acc[i][0], Dh * bf2f((unsigned short)(xv.x & 0xffffu)));
      o.y = fmaf(ex, acc[i][1], Dh * bf2f((unsigned short)(xv.x >> 16)));
      o.z = fmaf(ex, acc[i][2], Dh * bf2f((unsigned short)(xv.y & 0xffffu)));
      o.w = fmaf(ex, acc[i][3], Dh * bf2f((unsigned short)(xv.y >> 16)));
      *(float4*)&y[row * I_SZ + h * 64 + txp * 4] = o;
    }
  }
}

// ---------------------------------------------------------------------------
__global__ __launch_bounds__(256)
void ydiag_k(const unsigned short* __restrict__ convx,
             const float* __restrict__ dtv,
             const float* __restrict__ acs,
             const float* __restrict__ Gmat,
             float* __restrict__ y) {
  __shared__ float acs_s[256];
  __shared__ float xsT[64][68];
  __shared__ float Mt[64][66];
  int blk = blockIdx.x;
  int h = blk & 63;
  int bc = blk >> 6;
  int t = threadIdx.x;
  const int txp = t & 15, lq = t >> 4;
  acs_s[t] = acs[(long long)blk * 256 + t];
  const long long row0 = (long long)bc * 256;
  const float* Gb = Gmat + (long long)bc * 65536;
  for (int ltile = 0; ltile < 4; ltile++) {
    float acc[4][4] = {};
    for (int stile = 0; stile <= ltile; stile++) {
      __syncthreads();
#pragma unroll 4
      for (int q = 0; q < 16; q++) {
        int idx = t + 256 * q;
        int ss = idx >> 6, p = idx & 63;
        long long row = row0 + stile * 64 + ss;
        xsT[ss][p] = bf2f(convx[row * CONV_SZ + h * 64 + p]) * dtv[row * NH_SZ + h];
      }
#pragma unroll 4
      for (int q = 0; q < 16; q++) {
        int idx = t + 256 * q;
        int lr = idx >> 6, ss = idx & 63;
        int lg = ltile * 64 + lr, sg = stile * 64 + ss;
        float m = 0.f;
        if (sg <= lg) m = Gb[(long long)lg * 256 + sg] * expf(acs_s[lg] - acs_s[sg]);
        Mt[lr][ss] = m;
      }
      __syncthreads();
#pragma unroll 4
      for (int ss = 0; ss < 64; ss++) {
        float4 xv = *(const float4*)&xsT[ss][txp * 4];
        float m0 = Mt[lq * 4 + 0][ss];
        float m1 = Mt[lq * 4 + 1][ss];
        float m2 = Mt[lq * 4 + 2][ss];
        float m3 = Mt[lq * 4 + 3][ss];
        acc[0][0] = fmaf(m0, xv.x, acc[0][0]); acc[0][1] = fmaf(m0, xv.y, acc[0][1]);
        acc[0][2] = fmaf(m0, xv.z, acc[0][2]); acc[0][3] = fmaf(m0, xv.w, acc[0][3]);
        acc[1][0] = fmaf(m1, xv.x, acc[1][0]); acc[1][1] = fmaf(m1, xv.y, acc[1][1]);
        acc[1][2] = fmaf(m1, xv.z, acc[1][2]); acc[1][3] = fmaf(m1, xv.w, acc[1][3]);
        acc[2][0] = fmaf(m2, xv.x, acc[2][0]); acc[2][1] = fmaf(m2, xv.y, acc[2][1]);
        acc[2][2] = fmaf(m2, xv.z, acc[2][2]); acc[2][3] = fmaf(m2, xv.w, acc[2][3]);
        acc[3][0] = fmaf(m3, xv.x, acc[3][0]); acc[3][1] = fmaf(m3, xv.y, acc[3][1]);
        acc[3][2] = fmaf(m3, xv.z, acc[3][2]); acc[3][3] = fmaf(m3, xv.w, acc[3][3]);
      }
    }
#pragma unroll
    for (int i = 0; i < 4; i++) {
      long long row = row0 + ltile * 64 + lq * 4 + i;
      float* yp = &y[row * I_SZ + h * 64 + txp * 4];
      float4 cur = *(float4*)yp;
      cur.x += acc[i][0]; cur.y += acc[i][1]; cur.z += acc[i][2]; cur.w += acc[i][3];
      *(float4*)yp = cur;
    }
  }
}

// ---------------------------------------------------------------------------
__global__ __launch_bounds__(256)
void norm_k(const float* __restrict__ y,
            const unsigned short* __restrict__ proj,
            const void* __restrict__ nw,
            unsigned short* __restrict__ yfb, const int* __restrict__ flags) {
  __shared__ float red[4];
  __shared__ float sc_s;
  int row = blockIdx.x;
  int t = threadIdx.x;
  const int fn = flags[7];
  const float* yr = y + (long long)row * I_SZ;
  const unsigned short* zr = proj + (long long)row * PROJ_SZ;
  float g[16];
  float ss = 0.f;
#pragma unroll
  for (int q = 0; q < 4; q++) {
    int i0 = q * 1024 + t * 4;
    float4 yv = *(const float4*)&yr[i0];
    uint2 zv = *(const uint2*)&zr[i0];
    float z0 = bf2f((unsigned short)(zv.x & 0xffffu));
    float z1 = bf2f((unsigned short)(zv.x >> 16));
    float z2 = bf2f((unsigned short)(zv.y & 0xffffu));
    float z3 = bf2f((unsigned short)(zv.y >> 16));
    float g0 = yv.x * silu_f(z0), g1 = yv.y * silu_f(z1);
    float g2 = yv.z * silu_f(z2), g3 = yv.w * silu_f(z3);
    g[q * 4 + 0] = g0; g[q * 4 + 1] = g1; g[q * 4 + 2] = g2; g[q * 4 + 3] = g3;
    ss += g0 * g0 + g1 * g1 + g2 * g2 + g3 * g3;
  }
#pragma unroll
  for (int off = 32; off > 0; off >>= 1) ss += __shfl_down(ss, off, 64);
  if ((t & 63) == 0) red[t >> 6] = ss;
  __syncthreads();
  if (t == 0) sc_s = rsqrtf((red[0] + red[1] + red[2] + red[3]) * (1.f / 4096.f) + 1e-5f);
  __syncthreads();
  float sc = sc_s;
#pragma unroll
  for (int q = 0; q < 4; q++) {
    int i0 = q * 1024 + t * 4;
    float nv[4];
    load4(nw, i0, fn, nv);
    unsigned short o0 = f2bf(g[q * 4 + 0] * sc * nv[0]);
    unsigned short o1 = f2bf(g[q * 4 + 1] * sc * nv[1]);
    unsigned short o2 = f2bf(g[q * 4 + 2] * sc * nv[2]);
    unsigned short o3 = f2bf(g[q * 4 + 3] * sc * nv[3]);
    *(uint2*)&yfb[(long long)row * I_SZ + i0] =
        make_uint2((unsigned int)o0 | ((unsigned int)o1 << 16),
                   (unsigned int)o2 | ((unsigned int)o3 << 16));
  }
}

// ---------------------------------------------------------------------------
extern "C" void kernel_launch(void* const* d_in, const int* in_sizes, int n_in,
                              void* d_out, int out_size, void* d_ws, size_t ws_size,
                              hipStream_t stream) {
  const void* hs     = d_in[0];
  const void* W_in   = d_in[1];
  const void* conv_w = d_in[2];
  const void* conv_b = d_in[3];
  const void* dt_b   = d_in[4];
  const void* A_log  = d_in[5];
  const void* Dw     = d_in[6];
  const void* nw     = d_in[7];
  const void* W_out  = d_in[8];

  char* ws = (char*)d_ws;
  size_t off = 0;
  auto alloc = [&](size_t bytes) -> void* {
    void* p = ws + off;
    off += (bytes + 255) & ~(size_t)255;
    return p;
  };
  const long long ML = (long long)B_SZ * L_SZ;  // 4096 rows
  int* flags = (int*)alloc(64);
  unsigned short* proj  = (unsigned short*)alloc(ML * PROJ_SZ * 2);             // 66.5 MB
  unsigned short* convx = (unsigned short*)alloc(ML * CONV_SZ * 2);             // 34 MB
  float* dtv  = (float*)alloc(ML * NH_SZ * 4);                                  // 1 MB
  float* acsb = (float*)alloc((long long)B_SZ * NC_SZ * NH_SZ * CH_SZ * 4);     // 1 MB
  float* Gm   = (float*)alloc((long long)B_SZ * NC_SZ * CH_SZ * CH_SZ * 4);     // 4 MB
  float* stc  = (float*)alloc((long long)B_SZ * NC_SZ * NH_SZ * P_SZ * N_SZ * 4);  // 32 MB
  float* yb   = (float*)alloc(ML * I_SZ * 4);                                   // 64 MB
  unsigned short* yfb = (unsigned short*)stc;  // alias: stc dead after yoff_k
  (void)n_in; (void)out_size;
  if (off > ws_size) return;

  dim3 blk(256);
  // 0. per-tensor dtype detection
  detect_k<<<1, blk, 0, stream>>>(hs, W_in, conv_w, conv_b, dt_b, A_log, Dw, nw, W_out,
                                  in_sizes[0], in_sizes[1], in_sizes[2], in_sizes[3],
                                  in_sizes[4], in_sizes[5], in_sizes[6], in_sizes[7],
                                  in_sizes[8], flags);
  // 1. in-proj (MFMA): proj[4096,8512] = hs @ W_in^T  (bf16 out)
  gemm_mfma_k<0><<<dim3(67, 32, 1), blk, 0, stream>>>(
      hs, W_in, proj, 4096, PROJ_SZ, H_SZ, H_SZ, H_SZ, PROJ_SZ, flags, 0, 1, 15);
  // 2. conv + silu
  conv_silu_k<<<dim3((B_SZ * L_SZ * (CONV_SZ / 4) + 255) / 256), blk, 0, stream>>>(
      proj, conv_w, conv_b, convx, flags);
  // 3. dt
  dt_prep_k<<<dim3((unsigned)(ML * NH_SZ / 256)), blk, 0, stream>>>(proj, dt_b, dtv, flags);
  // 4. cumsum A*dt
  acs_scan_k<<<dim3(B_SZ * NC_SZ * NH_SZ), blk, 0, stream>>>(dtv, A_log, acsb, flags);
  // 5. G = Cc @ Bc^T per (b,chunk)  (fp32 out, vector path)
  gemm_bt_k<1><<<dim3(2, 2, 16), blk, 0, stream>>>(
      (const unsigned short*)convx + COFF, (const unsigned short*)convx + BOFF,
      Gm, 256, 256, 128, CONV_SZ, CONV_SZ, 256,
      (long long)256 * CONV_SZ, (long long)256 * CONV_SZ, 65536,
      flags, 15, 15, 15);
  // 6. per-chunk states
  chunk_states_k<<<dim3(1024), blk, 0, stream>>>(convx, dtv, acsb, stc);
  // 7. inter-chunk recurrence (in-place on stc)
  recur_k<<<dim3(B_SZ * NH_SZ), blk, 0, stream>>>(stc, acsb);
  // 8. Y_off + D*x
  yoff_k<<<dim3(1024), blk, 0, stream>>>(convx, stc, acsb, Dw, yb, flags);
  // 9. Y_diag
  ydiag_k<<<dim3(1024), blk, 0, stream>>>(convx, dtv, acsb, Gm, yb);
  // 10. gated RMSNorm
  norm_k<<<dim3((unsigned)ML), blk, 0, stream>>>(yb, proj, nw, yfb, flags);
  // 11. out-proj (MFMA): out = yf @ W_out^T; output dtype follows hs flag
  gemm_mfma_k<2><<<dim3(16, 32, 1), blk, 0, stream>>>(
      yfb, W_out, d_out, 4096, H_SZ, I_SZ, I_SZ, I_SZ, H_SZ, flags, 15, 8, 0);
}

// Round 5
// 843.332 us; speedup vs baseline: 4.0650x; 1.2222x over previous
//
#include <hip/hip_runtime.h>
#include <hip/hip_bf16.h>
#include <math.h>

// ---------------------------------------------------------------------------
// Mamba2 mixer forward, MI355X. Round 5: m97-style DMA GEMM.
// R4: 1031us; in-proj 403us @354TF, MfmaUtil 15% (f2bf VALU tax in K-loop).
// Changes:
//  - cvt_bf16_k: one-time fp32->bf16 conversion of hs/W_in/W_out (aliased
//    into the yb region; W_out converted after norm_k when yb is dead).
//  - gemm_dma_k: 128x128/BK=32 MFMA GEMM with global_load_lds width=16
//    (direct-to-LDS DMA, no staging VALU). Unpadded 32-elem LDS rows match
//    the wave-uniform-base+lane*16 scatter; frag ds_read_b128 is 2-way
//    bank-aliased (free, m136).
// ---------------------------------------------------------------------------

#define B_SZ 2
#define L_SZ 2048
#define H_SZ 2048
#define I_SZ 4096
#define N_SZ 128
#define NH_SZ 64
#define P_SZ 64
#define CH_SZ 256
#define NC_SZ 8
#define PROJ_SZ 8512
#define CONV_SZ 4352
#define XOFF 4096   // xBC start inside proj row
#define DTOFF 8448  // dt start inside proj row
#define BOFF 4096   // B start inside convx row
#define COFF 4224   // C start inside convx row

typedef __attribute__((ext_vector_type(8))) short short8_t;   // 8 bf16 frag
typedef __attribute__((ext_vector_type(4))) float float4_t;   // MFMA acc

// Direct-to-LDS DMA, 16 B per lane, wave-uniform LDS base.
#define GLDS(gp, lp)                                                   \
  __builtin_amdgcn_global_load_lds(                                    \
      (const __attribute__((address_space(1))) void*)(gp),             \
      (__attribute__((address_space(3))) void*)(lp), 16, 0, 0)

__device__ __forceinline__ float bf2f(unsigned short u) {
  union { unsigned int i; float f; } v; v.i = ((unsigned int)u) << 16; return v.f;
}
__device__ __forceinline__ unsigned short f2bf(float f) {
  union { float f; unsigned int i; } v; v.f = f;
  unsigned int b = v.i + 0x7fffu + ((v.i >> 16) & 1u);
  return (unsigned short)(b >> 16);
}
__device__ __forceinline__ void unpack8(uint4 v, float* f) {
  f[0] = bf2f((unsigned short)(v.x & 0xffffu)); f[1] = bf2f((unsigned short)(v.x >> 16));
  f[2] = bf2f((unsigned short)(v.y & 0xffffu)); f[3] = bf2f((unsigned short)(v.y >> 16));
  f[4] = bf2f((unsigned short)(v.z & 0xffffu)); f[5] = bf2f((unsigned short)(v.z >> 16));
  f[6] = bf2f((unsigned short)(v.w & 0xffffu)); f[7] = bf2f((unsigned short)(v.w >> 16));
}
__device__ __forceinline__ float silu_f(float x) { return x / (1.f + expf(-x)); }

__device__ __forceinline__ float load1(const void* p, long long e, int fp32) {
  return fp32 ? ((const float*)p)[e] : bf2f(((const unsigned short*)p)[e]);
}
__device__ __forceinline__ void load4(const void* p, long long e, int fp32, float* f) {
  if (fp32) {
    float4 a = *(const float4*)((const float*)p + e);
    f[0] = a.x; f[1] = a.y; f[2] = a.z; f[3] = a.w;
  } else {
    uint2 v = *(const uint2*)((const unsigned short*)p + e);
    f[0] = bf2f((unsigned short)(v.x & 0xffffu)); f[1] = bf2f((unsigned short)(v.x >> 16));
    f[2] = bf2f((unsigned short)(v.y & 0xffffu)); f[3] = bf2f((unsigned short)(v.y >> 16));
  }
}
__device__ __forceinline__ void load8(const void* p, long long e, int fp32, float* f) {
  if (fp32) {
    float4 a = *(const float4*)((const float*)p + e);
    float4 b = *(const float4*)((const float*)p + e + 4);
    f[0] = a.x; f[1] = a.y; f[2] = a.z; f[3] = a.w;
    f[4] = b.x; f[5] = b.y; f[6] = b.z; f[7] = b.w;
  } else {
    uint4 v = *(const uint4*)((const unsigned short*)p + e);
    unpack8(v, f);
  }
}

// ---------------------------------------------------------------------------
// Per-tensor dtype detector (confirmed working R3/R4).
// ---------------------------------------------------------------------------
__global__ void detect_k(const void* p0, const void* p1, const void* p2,
                         const void* p3, const void* p4, const void* p5,
                         const void* p6, const void* p7, const void* p8,
                         int n0, int n1, int n2, int n3, int n4, int n5,
                         int n6, int n7, int n8, int* flags) {
  __shared__ int pe, po;
  const void* ps[9] = {p0, p1, p2, p3, p4, p5, p6, p7, p8};
  int ns[9] = {n0, n1, n2, n3, n4, n5, n6, n7, n8};
  int t = threadIdx.x;
  for (int i = 0; i < 9; i++) {
    if (t == 0) { pe = 0; po = 0; }
    __syncthreads();
    int S = ns[i] < 256 ? ns[i] : 256;
    if (t < S) {
      unsigned short u = ((const unsigned short*)ps[i])[t];
      int ex = (u >> 7) & 0xFF;
      int plaus = ((u & 0x7FFFu) != 0) && (ex >= 0x70) && (ex <= 0x8F);
      if (plaus) { if (t & 1) atomicAdd(&po, 1); else atomicAdd(&pe, 1); }
    }
    __syncthreads();
    if (t == 0) flags[i] = (2 * pe < po) ? 1 : 0;
    __syncthreads();
  }
  if (t == 0) { flags[14] = 0; flags[15] = 0; }  // internal buffers: bf16
}

// ---------------------------------------------------------------------------
// fp32 (or bf16 passthrough) -> packed bf16. 8 elems/thread. n8 = n/8.
// ---------------------------------------------------------------------------
__global__ __launch_bounds__(256)
void cvt_bf16_k(const void* __restrict__ src, unsigned short* __restrict__ dst,
                long long n8, const int* __restrict__ flags, int fi) {
  long long g = (long long)blockIdx.x * 256 + threadIdx.x;
  if (g >= n8) return;
  long long e = g * 8;
  if (flags[fi]) {
    const float* s = (const float*)src + e;
    float4 a = *(const float4*)s;
    float4 b = *(const float4*)(s + 4);
    unsigned short o[8] = {f2bf(a.x), f2bf(a.y), f2bf(a.z), f2bf(a.w),
                           f2bf(b.x), f2bf(b.y), f2bf(b.z), f2bf(b.w)};
    *(uint4*)(dst + e) = *(const uint4*)o;
  } else {
    *(uint4*)(dst + e) = *(const uint4*)((const unsigned short*)src + e);
  }
}

// ---------------------------------------------------------------------------
// DMA MFMA GEMM: C[M,N] = A[M,K] @ B[N,K]^T, A/B packed bf16.
// 128x128 tile, BK=32, 256 thr (4 waves), global_load_lds width=16 staging.
// LDS tiles 128x32 bf16 unpadded (row stride 64 B) -> DMA scatter order is
// exactly row-major; 1 KB per wave per call; 2 calls per tile.
// OUT_MODE: 0 = bf16 out, 2 = runtime (flags[fo]: 1 -> fp32 out).
// Requires M%128==0, K%32==0. N edge: OOB B-row reads harmless (caller
// guarantees readable slack), stores guarded.
// ---------------------------------------------------------------------------
template <int OUT_MODE>
__global__ __launch_bounds__(256)
void gemm_dma_k(const unsigned short* __restrict__ A,
                const unsigned short* __restrict__ B,
                void* __restrict__ Cptr, int M, int N, int K,
                int lda, int ldb, int ldc,
                const int* __restrict__ flags, int fo) {
  __shared__ unsigned short As[128 * 32];
  __shared__ unsigned short Bs[128 * 32];
  const int t = threadIdx.x;
  const int lane = t & 63;
  const int wave = t >> 6;
  const int quad = lane >> 4;
  const int l16 = lane & 15;
  const int m0 = blockIdx.y * 128, n0 = blockIdx.x * 128;
  const int wm = (wave >> 1) * 64, wn = (wave & 1) * 64;
  const int ofp = (OUT_MODE == 2) ? flags[fo] : 0;

  float4_t acc[4][4];
#pragma unroll
  for (int i = 0; i < 4; i++)
#pragma unroll
    for (int j = 0; j < 4; j++) acc[i][j] = (float4_t){0.f, 0.f, 0.f, 0.f};

  // DMA mapping: call c covers rows c*64 + wave*16 .. +15; lane -> (row, kseg)
  const int rr = lane >> 2;        // row within 16-row group
  const int ks = (lane & 3) * 8;   // elem offset within 32-col tile row
  const long long aR0 = (long long)(m0 + wave * 16 + rr) * lda + ks;
  const long long aR1 = aR0 + (long long)64 * lda;
  const long long bR0 = (long long)(n0 + wave * 16 + rr) * ldb + ks;
  const long long bR1 = bR0 + (long long)64 * ldb;
  unsigned short* asd0 = &As[(wave * 16) * 32];
  unsigned short* asd1 = &As[(64 + wave * 16) * 32];
  unsigned short* bsd0 = &Bs[(wave * 16) * 32];
  unsigned short* bsd1 = &Bs[(64 + wave * 16) * 32];

  for (int k0 = 0; k0 < K; k0 += 32) {
    __syncthreads();  // prior frag reads done before DMA overwrite
    GLDS(A + aR0 + k0, asd0);
    GLDS(A + aR1 + k0, asd1);
    GLDS(B + bR0 + k0, bsd0);
    GLDS(B + bR1 + k0, bsd1);
    __syncthreads();  // vmcnt(0) drained -> tile visible
    short8_t afr[4], bfr[4];
#pragma unroll
    for (int i = 0; i < 4; i++)
      afr[i] = *(const short8_t*)&As[(wm + i * 16 + l16) * 32 + quad * 8];
#pragma unroll
    for (int j = 0; j < 4; j++)
      bfr[j] = *(const short8_t*)&Bs[(wn + j * 16 + l16) * 32 + quad * 8];
#pragma unroll
    for (int i = 0; i < 4; i++)
#pragma unroll
      for (int j = 0; j < 4; j++)
        acc[i][j] = __builtin_amdgcn_mfma_f32_16x16x32_bf16(
            afr[i], bfr[j], acc[i][j], 0, 0, 0);
  }
  // epilogue: D[m = quad*4+r][n = l16] per 16x16 tile
#pragma unroll
  for (int i = 0; i < 4; i++) {
#pragma unroll
    for (int r = 0; r < 4; r++) {
      const int m = m0 + wm + i * 16 + quad * 4 + r;
      const long long base = (long long)m * ldc;
#pragma unroll
      for (int j = 0; j < 4; j++) {
        const int n = n0 + wn + j * 16 + l16;
        if (n < N) {
          float v = acc[i][j][r];
          if (ofp) ((float*)Cptr)[base + n] = v;
          else     ((unsigned short*)Cptr)[base + n] = f2bf(v);
        }
      }
    }
  }
}

// ---------------------------------------------------------------------------
// Vector GEMM (small G = Cc@Bc^T batch). fp32 acc. OUT_MODE 1 = fp32 out.
// ---------------------------------------------------------------------------
template <int OUT_MODE>
__global__ __launch_bounds__(256)
void gemm_bt_k(const void* __restrict__ A, const void* __restrict__ B,
               void* __restrict__ Cptr, int M, int N, int K,
               int lda, int ldb, int ldc,
               long long sA, long long sB, long long sC,
               const int* __restrict__ flags, int fa, int fb, int fo) {
  __shared__ float As[128][20];
  __shared__ float Bs[128][20];
  const int t = threadIdx.x;
  const int tx = t & 15, ty = t >> 4;
  const int m0 = blockIdx.y * 128, n0 = blockIdx.x * 128;
  const int afp = flags[fa], bfp = flags[fb];
  const int ofp = (OUT_MODE == 2) ? flags[fo] : (OUT_MODE == 1);
  const long long zoff = (long long)blockIdx.z;
  float* Cf = (float*)Cptr + zoff * sC;
  unsigned short* Cb = (unsigned short*)Cptr + zoff * sC;

  float acc[8][8];
#pragma unroll
  for (int i = 0; i < 8; i++)
#pragma unroll
    for (int j = 0; j < 8; j++) acc[i][j] = 0.f;

  const int rowS = t >> 1;
  const int kof  = (t & 1) * 8;
  const long long aRow = zoff * sA + (long long)(m0 + rowS) * lda + kof;
  const long long bRow = zoff * sB + (long long)(n0 + rowS) * ldb + kof;
  const bool bOK = (n0 + rowS) < N;

  for (int k0 = 0; k0 < K; k0 += 16) {
    float af[8], bf[8];
    load8(A, aRow + k0, afp, af);
    if (bOK) load8(B, bRow + k0, bfp, bf);
    else { bf[0]=bf[1]=bf[2]=bf[3]=bf[4]=bf[5]=bf[6]=bf[7]=0.f; }
    __syncthreads();
    *(float4*)&As[rowS][kof]     = make_float4(af[0], af[1], af[2], af[3]);
    *(float4*)&As[rowS][kof + 4] = make_float4(af[4], af[5], af[6], af[7]);
    *(float4*)&Bs[rowS][kof]     = make_float4(bf[0], bf[1], bf[2], bf[3]);
    *(float4*)&Bs[rowS][kof + 4] = make_float4(bf[4], bf[5], bf[6], bf[7]);
    __syncthreads();
#pragma unroll
    for (int kk = 0; kk < 16; kk += 2) {
      float2 a2[8], b2[8];
#pragma unroll
      for (int i = 0; i < 8; i++) a2[i] = *(const float2*)&As[ty + 16 * i][kk];
#pragma unroll
      for (int j = 0; j < 8; j++) b2[j] = *(const float2*)&Bs[tx + 16 * j][kk];
#pragma unroll
      for (int i = 0; i < 8; i++)
#pragma unroll
        for (int j = 0; j < 8; j++) {
          acc[i][j] = fmaf(a2[i].x, b2[j].x, acc[i][j]);
          acc[i][j] = fmaf(a2[i].y, b2[j].y, acc[i][j]);
        }
    }
  }
#pragma unroll
  for (int i = 0; i < 8; i++) {
    const int m = m0 + ty + 16 * i;
    const long long base = (long long)m * ldc;
#pragma unroll
    for (int j = 0; j < 8; j++) {
      const int n = n0 + tx + 16 * j;
      if (n < N) {
        if (ofp) Cf[base + n] = acc[i][j];
        else     Cb[base + n] = f2bf(acc[i][j]);
      }
    }
  }
}

// ---------------------------------------------------------------------------
// Depthwise causal conv (K=4) + bias + SiLU over xBC columns of proj.
// ---------------------------------------------------------------------------
__global__ __launch_bounds__(256)
void conv_silu_k(const unsigned short* __restrict__ proj,
                 const void* __restrict__ cw,
                 const void* __restrict__ cb,
                 unsigned short* __restrict__ convx,
                 const int* __restrict__ flags) {
  const int total = B_SZ * L_SZ * (CONV_SZ / 4);
  int g = blockIdx.x * 256 + threadIdx.x;
  if (g >= total) return;
  const int fw = flags[2], fb = flags[3];
  int c4 = g % (CONV_SZ / 4);
  int bl = g / (CONV_SZ / 4);
  int l = bl & (L_SZ - 1);
  int ch = c4 * 4;
  float w0[8], w1[8];
  load8(cw, (long long)ch * 4, fw, w0);
  load8(cw, (long long)ch * 4 + 8, fw, w1);
  float accv[4];
  load4(cb, ch, fb, accv);
  float acc0 = accv[0], acc1 = accv[1], acc2 = accv[2], acc3 = accv[3];
  const long long rb = (long long)(bl - l);
#pragma unroll
  for (int k = 0; k < 4; k++) {
    int ls = l - 3 + k;
    if (ls < 0) continue;
    uint2 xv = *(const uint2*)(proj + (rb + ls) * PROJ_SZ + XOFF + ch);
    float x0 = bf2f((unsigned short)(xv.x & 0xffffu));
    float x1 = bf2f((unsigned short)(xv.x >> 16));
    float x2 = bf2f((unsigned short)(xv.y & 0xffffu));
    float x3 = bf2f((unsigned short)(xv.y >> 16));
    acc0 = fmaf(x0, w0[k], acc0);
    acc1 = fmaf(x1, w0[4 + k], acc1);
    acc2 = fmaf(x2, w1[k], acc2);
    acc3 = fmaf(x3, w1[4 + k], acc3);
  }
  unsigned short o0 = f2bf(silu_f(acc0));
  unsigned short o1 = f2bf(silu_f(acc1));
  unsigned short o2 = f2bf(silu_f(acc2));
  unsigned short o3 = f2bf(silu_f(acc3));
  *(uint2*)(convx + (long long)bl * CONV_SZ + ch) =
      make_uint2((unsigned int)o0 | ((unsigned int)o1 << 16),
                 (unsigned int)o2 | ((unsigned int)o3 << 16));
}

// ---------------------------------------------------------------------------
__global__ __launch_bounds__(256)
void dt_prep_k(const unsigned short* __restrict__ proj,
               const void* __restrict__ dt_bias,
               float* __restrict__ dtv, const int* __restrict__ flags) {
  int g = blockIdx.x * 256 + threadIdx.x;
  int h = g & 63;
  long long bl = g >> 6;
  float v = bf2f(proj[bl * PROJ_SZ + DTOFF + h]) + load1(dt_bias, h, flags[4]);
  float sp = (v > 20.f) ? v : log1pf(expf(v));
  dtv[g] = sp;
}

// ---------------------------------------------------------------------------
__global__ __launch_bounds__(256)
void acs_scan_k(const float* __restrict__ dtv,
                const void* __restrict__ A_log,
                float* __restrict__ acs, const int* __restrict__ flags) {
  __shared__ float sd[256];
  int blk = blockIdx.x;
  int h = blk & 63;
  int bc = blk >> 6;
  int l = threadIdx.x;
  float Ah = -expf(load1(A_log, h, flags[5]));
  long long row = (long long)bc * CH_SZ + l;
  sd[l] = Ah * dtv[row * NH_SZ + h];
  for (int off = 1; off < 256; off <<= 1) {
    __syncthreads();
    float tv = (l >= off) ? sd[l - off] : 0.f;
    __syncthreads();
    sd[l] += tv;
  }
  acs[(long long)blk * CH_SZ + l] = sd[l];
}

// ---------------------------------------------------------------------------
__global__ __launch_bounds__(256)
void chunk_states_k(const unsigned short* __restrict__ convx,
                    const float* __restrict__ dtv,
                    const float* __restrict__ acs,
                    float* __restrict__ stc) {
  __shared__ float Bw[32][128];
  __shared__ float xw[32][64];
  int blk = blockIdx.x;
  int h = blk & 63;
  int bc = blk >> 6;
  int t = threadIdx.x;
  const int p0 = (t & 15) * 4, n0 = (t >> 4) * 8;
  const float* acsb = acs + (long long)blk * 256;
  const float alast = acsb[255];
  float acc[4][8];
#pragma unroll
  for (int i = 0; i < 4; i++)
#pragma unroll
    for (int j = 0; j < 8; j++) acc[i][j] = 0.f;
  const long long row0 = (long long)bc * 256;

  for (int lt0 = 0; lt0 < 256; lt0 += 32) {
    __syncthreads();
#pragma unroll
    for (int q = 0; q < 4; q++) {
      int idx4 = (t + 256 * q) * 4;
      int r = idx4 >> 7, n = idx4 & 127;
      uint2 v = *(const uint2*)(convx + (row0 + lt0 + r) * CONV_SZ + BOFF + n);
      Bw[r][n]     = bf2f((unsigned short)(v.x & 0xffffu));
      Bw[r][n + 1] = bf2f((unsigned short)(v.x >> 16));
      Bw[r][n + 2] = bf2f((unsigned short)(v.y & 0xffffu));
      Bw[r][n + 3] = bf2f((unsigned short)(v.y >> 16));
    }
#pragma unroll
    for (int q = 0; q < 2; q++) {
      int idx4 = (t + 256 * q) * 4;
      int r = idx4 >> 6, p = idx4 & 63;
      long long lg = row0 + lt0 + r;
      float sc = dtv[lg * NH_SZ + h] * expf(alast - acsb[lt0 + r]);
      uint2 v = *(const uint2*)(convx + lg * CONV_SZ + h * 64 + p);
      xw[r][p]     = bf2f((unsigned short)(v.x & 0xffffu)) * sc;
      xw[r][p + 1] = bf2f((unsigned short)(v.x >> 16)) * sc;
      xw[r][p + 2] = bf2f((unsigned short)(v.y & 0xffffu)) * sc;
      xw[r][p + 3] = bf2f((unsigned short)(v.y >> 16)) * sc;
    }
    __syncthreads();
#pragma unroll 4
    for (int lt = 0; lt < 32; lt++) {
      float4 xv = *(const float4*)&xw[lt][p0];
      float4 b0 = *(const float4*)&Bw[lt][n0];
      float4 b1 = *(const float4*)&Bw[lt][n0 + 4];
      float xa[4] = {xv.x, xv.y, xv.z, xv.w};
      float ba[8] = {b0.x, b0.y, b0.z, b0.w, b1.x, b1.y, b1.z, b1.w};
#pragma unroll
      for (int i = 0; i < 4; i++)
#pragma unroll
        for (int j = 0; j < 8; j++) acc[i][j] = fmaf(xa[i], ba[j], acc[i][j]);
    }
  }
  float* outb = stc + (long long)blk * 8192;
#pragma unroll
  for (int i = 0; i < 4; i++) {
    *(float4*)&outb[(p0 + i) * 128 + n0] =
        make_float4(acc[i][0], acc[i][1], acc[i][2], acc[i][3]);
    *(float4*)&outb[(p0 + i) * 128 + n0 + 4] =
        make_float4(acc[i][4], acc[i][5], acc[i][6], acc[i][7]);
  }
}

// ---------------------------------------------------------------------------
__global__ __launch_bounds__(256)
void recur_k(float* __restrict__ stc, const float* __restrict__ acs) {
  int blk = blockIdx.x;
  int b = blk >> 6, h = blk & 63;
  int t = threadIdx.x;
  float S[32];
#pragma unroll
  for (int j = 0; j < 32; j++) S[j] = 0.f;
  for (int z = 0; z < 8; z++) {
    long long bz = ((long long)b * 8 + z) * 64 + h;
    long long base = bz * 8192;
    float e = expf(acs[bz * 256 + 255]);
#pragma unroll
    for (int j = 0; j < 32; j++) {
      int idx = j * 256 + t;
      float cs = stc[base + idx];
      stc[base + idx] = S[j];
      S[j] = fmaf(e, S[j], cs);
    }
  }
}

// ---------------------------------------------------------------------------
__global__ __launch_bounds__(256)
void yoff_k(const unsigned short* __restrict__ convx,
            const float* __restrict__ sti,
            const float* __restrict__ acs,
            const void* __restrict__ Dw,
            float* __restrict__ y, const int* __restrict__ flags) {
  __shared__ float SIt[128][68];
  __shared__ unsigned short Ct[64][128];
  int blk = blockIdx.x;
  int h = blk & 63;
  int bc = blk >> 6;
  int t = threadIdx.x;
  const int txp = t & 15, lq = t >> 4;
  const float Dh = load1(Dw, h, flags[6]);
  const float* sib = sti + (long long)blk * 8192;
#pragma unroll 4
  for (int q = 0; q < 32; q++) {
    int idx = t + 256 * q;
    SIt[idx & 127][idx >> 7] = sib[idx];
  }
  const float* acsb = acs + (long long)blk * 256;
  const long long row0 = (long long)bc * 256;
  for (int ltile = 0; ltile < 4; ltile++) {
    __syncthreads();
#pragma unroll 4
    for (int q = 0; q < 32; q++) {
      int idx = t + 256 * q;
      int lr = idx >> 7, n = idx & 127;
      Ct[lr][n] = convx[(row0 + ltile * 64 + lr) * CONV_SZ + COFF + n];
    }
    __syncthreads();
    float acc[4][4] = {};
#pragma unroll 4
    for (int n = 0; n < 128; n++) {
      float4 sv = *(const float4*)&SIt[n][txp * 4];
      float c0 = bf2f(Ct[lq * 4 + 0][n]);
      float c1 = bf2f(Ct[lq * 4 + 1][n]);
      float c2 = bf2f(Ct[lq * 4 + 2][n]);
      float c3 = bf2f(Ct[lq * 4 + 3][n]);
      acc[0][0] = fmaf(c0, sv.x, acc[0][0]); acc[0][1] = fmaf(c0, sv.y, acc[0][1]);
      acc[0][2] = fmaf(c0, sv.z, acc[0][2]); acc[0][3] = fmaf(c0, sv.w, acc[0][3]);
      acc[1][0] = fmaf(c1, sv.x, acc[1][0]); acc[1][1] = fmaf(c1, sv.y, acc[1][1]);
      acc[1][2] = fmaf(c1, sv.z, acc[1][2]); acc[1][3] = fmaf(c1, sv.w, acc[1][3]);
      acc[2][0] = fmaf(c2, sv.x, acc[2][0]); acc[2][1] = fmaf(c2, sv.y, acc[2][1]);
      acc[2][2] = fmaf(c2, sv.z, acc[2][2]); acc[2][3] = fmaf(c2, sv.w, acc[2][3]);
      acc[3][0] = fmaf(c3, sv.x, acc[3][0]); acc[3][1] = fmaf(c3, sv.y, acc[3][1]);
      acc[3][2] = fmaf(c3, sv.z, acc[3][2]); acc[3][3] = fmaf(c3, sv.w, acc[3][3]);
    }
#pragma unroll
    for (int i = 0; i < 4; i++) {
      int lloc = ltile * 64 + lq * 4 + i;
      long long row = row0 + lloc;
      float ex = expf(acsb[lloc]);
      uint2 xv = *(const uint2*)(convx + row * CONV_SZ + h * 64 + txp * 4);
      float4 o;
      o.x = fmaf(ex, acc[i][0], Dh * bf2f((unsigned short)(xv.x & 0xffffu)));
      o.y = fmaf(ex, acc[i][1], Dh * bf2f((unsigned short)(xv.x >> 16)));
      o.z = fmaf(ex, acc[i][2], Dh * bf2f((unsigned short)(xv.y & 0xffffu)));
      o.w = fmaf(ex, acc[i][3], Dh * bf2f((unsigned short)(xv.y >> 16)));
      *(float4*)&y[row * I_SZ + h * 64 + txp * 4] = o;
    }
  }
}

// ---------------------------------------------------------------------------
__global__ __launch_bounds__(256)
void ydiag_k(const unsigned short* __restrict__ convx,
             const float* __restrict__ dtv,
             const float* __restrict__ acs,
             const float* __restrict__ Gmat,
             float* __restrict__ y) {
  __shared__ float acs_s[256];
  __shared__ float xsT[64][68];
  __shared__ float Mt[64][66];
  int blk = blockIdx.x;
  int h = blk & 63;
  int bc = blk >> 6;
  int t = threadIdx.x;
  const int txp = t & 15, lq = t >> 4;
  acs_s[t] = acs[(long long)blk * 256 + t];
  const long long row0 = (long long)bc * 256;
  const float* Gb = Gmat + (long long)bc * 65536;
  for (int ltile = 0; ltile < 4; ltile++) {
    float acc[4][4] = {};
    for (int stile = 0; stile <= ltile; stile++) {
      __syncthreads();
#pragma unroll 4
      for (int q = 0; q < 16; q++) {
        int idx = t + 256 * q;
        int ss = idx >> 6, p = idx & 63;
        long long row = row0 + stile * 64 + ss;
        xsT[ss][p] = bf2f(convx[row * CONV_SZ + h * 64 + p]) * dtv[row * NH_SZ + h];
      }
#pragma unroll 4
      for (int q = 0; q < 16; q++) {
        int idx = t + 256 * q;
        int lr = idx >> 6, ss = idx & 63;
        int lg = ltile * 64 + lr, sg = stile * 64 + ss;
        float m = 0.f;
        if (sg <= lg) m = Gb[(long long)lg * 256 + sg] * expf(acs_s[lg] - acs_s[sg]);
        Mt[lr][ss] = m;
      }
      __syncthreads();
#pragma unroll 4
      for (int ss = 0; ss < 64; ss++) {
        float4 xv = *(const float4*)&xsT[ss][txp * 4];
        float m0 = Mt[lq * 4 + 0][ss];
        float m1 = Mt[lq * 4 + 1][ss];
        float m2 = Mt[lq * 4 + 2][ss];
        float m3 = Mt[lq * 4 + 3][ss];
        acc[0][0] = fmaf(m0, xv.x, acc[0][0]); acc[0][1] = fmaf(m0, xv.y, acc[0][1]);
        acc[0][2] = fmaf(m0, xv.z, acc[0][2]); acc[0][3] = fmaf(m0, xv.w, acc[0][3]);
        acc[1][0] = fmaf(m1, xv.x, acc[1][0]); acc[1][1] = fmaf(m1, xv.y, acc[1][1]);
        acc[1][2] = fmaf(m1, xv.z, acc[1][2]); acc[1][3] = fmaf(m1, xv.w, acc[1][3]);
        acc[2][0] = fmaf(m2, xv.x, acc[2][0]); acc[2][1] = fmaf(m2, xv.y, acc[2][1]);
        acc[2][2] = fmaf(m2, xv.z, acc[2][2]); acc[2][3] = fmaf(m2, xv.w, acc[2][3]);
        acc[3][0] = fmaf(m3, xv.x, acc[3][0]); acc[3][1] = fmaf(m3, xv.y, acc[3][1]);
        acc[3][2] = fmaf(m3, xv.z, acc[3][2]); acc[3][3] = fmaf(m3, xv.w, acc[3][3]);
      }
    }
#pragma unroll
    for (int i = 0; i < 4; i++) {
      long long row = row0 + ltile * 64 + lq * 4 + i;
      float* yp = &y[row * I_SZ + h * 64 + txp * 4];
      float4 cur = *(float4*)yp;
      cur.x += acc[i][0]; cur.y += acc[i][1]; cur.z += acc[i][2]; cur.w += acc[i][3];
      *(float4*)yp = cur;
    }
  }
}

// ---------------------------------------------------------------------------
__global__ __launch_bounds__(256)
void norm_k(const float* __restrict__ y,
            const unsigned short* __restrict__ proj,
            const void* __restrict__ nw,
            unsigned short* __restrict__ yfb, const int* __restrict__ flags) {
  __shared__ float red[4];
  __shared__ float sc_s;
  int row = blockIdx.x;
  int t = threadIdx.x;
  const int fn = flags[7];
  const float* yr = y + (long long)row * I_SZ;
  const unsigned short* zr = proj + (long long)row * PROJ_SZ;
  float g[16];
  float ss = 0.f;
#pragma unroll
  for (int q = 0; q < 4; q++) {
    int i0 = q * 1024 + t * 4;
    float4 yv = *(const float4*)&yr[i0];
    uint2 zv = *(const uint2*)&zr[i0];
    float z0 = bf2f((unsigned short)(zv.x & 0xffffu));
    float z1 = bf2f((unsigned short)(zv.x >> 16));
    float z2 = bf2f((unsigned short)(zv.y & 0xffffu));
    float z3 = bf2f((unsigned short)(zv.y >> 16));
    float g0 = yv.x * silu_f(z0), g1 = yv.y * silu_f(z1);
    float g2 = yv.z * silu_f(z2), g3 = yv.w * silu_f(z3);
    g[q * 4 + 0] = g0; g[q * 4 + 1] = g1; g[q * 4 + 2] = g2; g[q * 4 + 3] = g3;
    ss += g0 * g0 + g1 * g1 + g2 * g2 + g3 * g3;
  }
#pragma unroll
  for (int off = 32; off > 0; off >>= 1) ss += __shfl_down(ss, off, 64);
  if ((t & 63) == 0) red[t >> 6] = ss;
  __syncthreads();
  if (t == 0) sc_s = rsqrtf((red[0] + red[1] + red[2] + red[3]) * (1.f / 4096.f) + 1e-5f);
  __syncthreads();
  float sc = sc_s;
#pragma unroll
  for (int q = 0; q < 4; q++) {
    int i0 = q * 1024 + t * 4;
    float nv[4];
    load4(nw, i0, fn, nv);
    unsigned short o0 = f2bf(g[q * 4 + 0] * sc * nv[0]);
    unsigned short o1 = f2bf(g[q * 4 + 1] * sc * nv[1]);
    unsigned short o2 = f2bf(g[q * 4 + 2] * sc * nv[2]);
    unsigned short o3 = f2bf(g[q * 4 + 3] * sc * nv[3]);
    *(uint2*)&yfb[(long long)row * I_SZ + i0] =
        make_uint2((unsigned int)o0 | ((unsigned int)o1 << 16),
                   (unsigned int)o2 | ((unsigned int)o3 << 16));
  }
}

// ---------------------------------------------------------------------------
extern "C" void kernel_launch(void* const* d_in, const int* in_sizes, int n_in,
                              void* d_out, int out_size, void* d_ws, size_t ws_size,
                              hipStream_t stream) {
  const void* hs     = d_in[0];
  const void* W_in   = d_in[1];
  const void* conv_w = d_in[2];
  const void* conv_b = d_in[3];
  const void* dt_b   = d_in[4];
  const void* A_log  = d_in[5];
  const void* Dw     = d_in[6];
  const void* nw     = d_in[7];
  const void* W_out  = d_in[8];

  char* ws = (char*)d_ws;
  size_t off = 0;
  auto alloc = [&](size_t bytes) -> void* {
    void* p = ws + off;
    off += (bytes + 255) & ~(size_t)255;
    return p;
  };
  const long long ML = (long long)B_SZ * L_SZ;  // 4096 rows
  int* flags = (int*)alloc(64);
  unsigned short* proj  = (unsigned short*)alloc(ML * PROJ_SZ * 2);             // 66.5 MB
  unsigned short* convx = (unsigned short*)alloc(ML * CONV_SZ * 2);             // 34 MB
  float* dtv  = (float*)alloc(ML * NH_SZ * 4);                                  // 1 MB
  float* acsb = (float*)alloc((long long)B_SZ * NC_SZ * NH_SZ * CH_SZ * 4);     // 1 MB
  float* Gm   = (float*)alloc((long long)B_SZ * NC_SZ * CH_SZ * CH_SZ * 4);     // 4 MB
  float* stc  = (float*)alloc((long long)B_SZ * NC_SZ * NH_SZ * P_SZ * N_SZ * 4);  // 32 MB
  float* yb   = (float*)alloc(ML * I_SZ * 4);                                   // 64 MB
  unsigned short* yfb = (unsigned short*)stc;  // alias: stc dead after yoff_k
  // bf16 staging copies alias the yb region (dead until yoff_k / after norm_k)
  unsigned short* hs_bf   = (unsigned short*)yb;                 // 16 MB
  unsigned short* Win_bf  = (unsigned short*)yb + 8388608;       // 34.9 MB (ends <51MB)
  unsigned short* Wout_bf = (unsigned short*)yb;                 // 16 MB (after norm_k)
  (void)n_in; (void)out_size;
  if (off > ws_size) return;

  dim3 blk(256);
  // 0. per-tensor dtype detection
  detect_k<<<1, blk, 0, stream>>>(hs, W_in, conv_w, conv_b, dt_b, A_log, Dw, nw, W_out,
                                  in_sizes[0], in_sizes[1], in_sizes[2], in_sizes[3],
                                  in_sizes[4], in_sizes[5], in_sizes[6], in_sizes[7],
                                  in_sizes[8], flags);
  // 0a. convert hs, W_in to packed bf16
  cvt_bf16_k<<<dim3(4096), blk, 0, stream>>>(hs, hs_bf, 1048576LL, flags, 0);
  cvt_bf16_k<<<dim3(8512), blk, 0, stream>>>(W_in, Win_bf, 2179072LL, flags, 1);
  // 1. in-proj (DMA MFMA): proj[4096,8512] = hs @ W_in^T  (bf16 out)
  gemm_dma_k<0><<<dim3(67, 32, 1), blk, 0, stream>>>(
      hs_bf, Win_bf, proj, 4096, PROJ_SZ, H_SZ, H_SZ, H_SZ, PROJ_SZ, flags, 15);
  // 2. conv + silu
  conv_silu_k<<<dim3((B_SZ * L_SZ * (CONV_SZ / 4) + 255) / 256), blk, 0, stream>>>(
      proj, conv_w, conv_b, convx, flags);
  // 3. dt
  dt_prep_k<<<dim3((unsigned)(ML * NH_SZ / 256)), blk, 0, stream>>>(proj, dt_b, dtv, flags);
  // 4. cumsum A*dt
  acs_scan_k<<<dim3(B_SZ * NC_SZ * NH_SZ), blk, 0, stream>>>(dtv, A_log, acsb, flags);
  // 5. G = Cc @ Bc^T per (b,chunk)  (fp32 out, vector path)
  gemm_bt_k<1><<<dim3(2, 2, 16), blk, 0, stream>>>(
      (const unsigned short*)convx + COFF, (const unsigned short*)convx + BOFF,
      Gm, 256, 256, 128, CONV_SZ, CONV_SZ, 256,
      (long long)256 * CONV_SZ, (long long)256 * CONV_SZ, 65536,
      flags, 15, 15, 15);
  // 6. per-chunk states
  chunk_states_k<<<dim3(1024), blk, 0, stream>>>(convx, dtv, acsb, stc);
  // 7. inter-chunk recurrence (in-place on stc)
  recur_k<<<dim3(B_SZ * NH_SZ), blk, 0, stream>>>(stc, acsb);
  // 8. Y_off + D*x  (overwrites yb; hs_bf/Win_bf dead)
  yoff_k<<<dim3(1024), blk, 0, stream>>>(convx, stc, acsb, Dw, yb, flags);
  // 9. Y_diag
  ydiag_k<<<dim3(1024), blk, 0, stream>>>(convx, dtv, acsb, Gm, yb);
  // 10. gated RMSNorm
  norm_k<<<dim3((unsigned)ML), blk, 0, stream>>>(yb, proj, nw, yfb, flags);
  // 10a. convert W_out (yb now dead)
  cvt_bf16_k<<<dim3(4096), blk, 0, stream>>>(W_out, Wout_bf, 1048576LL, flags, 8);
  // 11. out-proj (DMA MFMA): out = yf @ W_out^T; output dtype follows hs flag
  gemm_dma_k<2><<<dim3(16, 32, 1), blk, 0, stream>>>(
      yfb, Wout_bf, d_out, 4096, H_SZ, I_SZ, I_SZ, I_SZ, H_SZ, flags, 0);
}